// Round 14
// baseline (241.478 us; speedup 1.0000x reference)
//
#include <hip/hip_runtime.h>
#include <stdint.h>

// Problem constants (B=4, T=2048, C=1024, H=16, D=64)
#define T_SEQ 2048
#define CDIM  1024
#define NH    16
#define DH    64
#define BATCH 4
#define MROWS (BATCH * T_SEQ)   // 8192
#define N3    (3 * CDIM)        // 3072
#define NEGBIG -1e30f

typedef unsigned short u16;
typedef __attribute__((ext_vector_type(8))) __bf16 bf16x8;
typedef __attribute__((ext_vector_type(4))) __bf16 bf16x4;
typedef __attribute__((ext_vector_type(8))) unsigned short u16x8;
typedef __attribute__((ext_vector_type(4))) float f32x4;
typedef __attribute__((ext_vector_type(16))) float f32x16;
typedef __attribute__((ext_vector_type(4))) unsigned int u32x4;

__device__ inline u16 f2bf(float f) {
  uint32_t u = __builtin_bit_cast(uint32_t, f);
  u += 0x7FFFu + ((u >> 16) & 1u);   // RNE; inputs finite
  return (u16)(u >> 16);
}

// async global->LDS, 16B per lane; LDS dest = wave-uniform base + lane*16
__device__ inline void gld_lds16(const void* g, void* l) {
  __builtin_amdgcn_global_load_lds(
      (const __attribute__((address_space(1))) void*)g,
      (__attribute__((address_space(3))) void*)l, 16, 0, 0);
}

// ---------------- aux kernels ----------------

__global__ __launch_bounds__(256) void cvt_f32_bf16(
    const float* __restrict__ in, u16* __restrict__ out, int n) {
  int i = (blockIdx.x * 256 + threadIdx.x) * 4;
  if (i >= n) return;
  float4 v = *(const float4*)&in[i];
  ushort4 o; o.x = f2bf(v.x); o.y = f2bf(v.y); o.z = f2bf(v.z); o.w = f2bf(v.w);
  *(ushort4*)&out[i] = o;
}

// W [K][N] fp32 -> WT [N][K] bf16, LDS-tiled (coalesced both sides)
__global__ __launch_bounds__(256) void wt_tiled(
    const float* __restrict__ W, u16* __restrict__ WT, int K, int N) {
  __shared__ float tile[64][65];
  const int k0 = blockIdx.y * 64, n0 = blockIdx.x * 64;
  const int t = threadIdx.x, cr = t >> 6, cc = t & 63;
#pragma unroll
  for (int i = 0; i < 16; i++) {
    int r = i * 4 + cr;
    tile[r][cc] = W[(size_t)(k0 + r) * N + n0 + cc];
  }
  __syncthreads();
#pragma unroll
  for (int i = 0; i < 16; i++) {
    int r = i * 4 + cr;  // output row (n)
    WT[(size_t)(n0 + r) * K + k0 + cc] = f2bf(tile[cc][r]);
  }
}

// lengths[b] = count of non-padded rows; auto-detect int32 vs byte mask.
__global__ __launch_bounds__(256) void len_kernel(
    const void* __restrict__ maskp, int* __restrict__ lengths) {
  __shared__ int flag;
  __shared__ int red[256];
  const int t = threadIdx.x, b = blockIdx.x;
  if (t == 0) flag = 0;
  __syncthreads();
  const uint32_t* mw = (const uint32_t*)maskp;
  int f = 0;
  for (int i = t; i < 2048; i += 256) f |= (mw[i] > 1u) ? 1 : 0;
  if (f) atomicOr(&flag, 1);
  __syncthreads();
  int cnt = 0;
  if (flag) {
    const uint8_t* mb = (const uint8_t*)maskp;
    for (int i = t; i < T_SEQ; i += 256) cnt += (mb[(size_t)b * T_SEQ + i] == 0);
  } else {
    const int* mi = (const int*)maskp;
    for (int i = t; i < T_SEQ; i += 256) cnt += (mi[(size_t)b * T_SEQ + i] == 0);
  }
  red[t] = cnt;
  __syncthreads();
  for (int s = 128; s > 0; s >>= 1) {
    if (t < s) red[t] += red[t + s];
    __syncthreads();
  }
  if (t == 0) lengths[b] = red[0];
}

// ------- QKV GEMM, 256x256 tile, 8 waves, phase-split counted-vmcnt -------
// C[M,3C] = A[M,K] * Bt[3C,K]^T + bias; scatter Q/K [b,h,t,d], V -> Vt
// [b,h,d,t]. T3+T4 schedule: ring-2 LDS (128KB), burst-stage K-tile it+1 at
// iter top -> vmcnt(8) (never 0 until last iter) + barrier; 4 phases per
// K-tile, each {12 ds_read quad frags; bar; lgkmcnt(0)+sched_barrier;
// setprio(1); 16 MFMA; setprio(0); bar}. Writer/reader separated by the
// iter-end barrier. Epilogue = r13-proven LDS bounce scaled to 256^2.
__global__ __launch_bounds__(512, 2) void gemm256_qkv(
    const u16* __restrict__ A, const u16* __restrict__ Bt,
    const float* __restrict__ bias,
    u16* __restrict__ Qb, u16* __restrict__ Kb, u16* __restrict__ Vt,
    const int* __restrict__ lengths) {
  __shared__ __attribute__((aligned(16))) char smem[131072];
  const int t = threadIdx.x;
  const int lane = t & 63, wid = t >> 6;
  const int wm = wid >> 2, wn = wid & 3;       // 2(M) x 4(N) waves
  const int r16 = lane & 15, kg = lane >> 4;
  const int m0 = blockIdx.y * 256, n0 = blockIdx.x * 256;
  const int b = m0 >> 11, tt0 = m0 & 2047;
  if (tt0 >= lengths[b]) return;               // fully padded M-tile (uniform)

  f32x4 acc[8][4];
#pragma unroll
  for (int i = 0; i < 8; i++)
#pragma unroll
    for (int j = 0; j < 4; j++) acc[i][j] = (f32x4){0.f, 0.f, 0.f, 0.f};

  auto STAGE_TILE = [&](int buf, int kt) {     // 8 loads/thread (A + B tile)
    const int k0 = kt * 64;
    char* Ad = smem + buf * 32768;
    char* Bd = smem + 65536 + buf * 32768;
#pragma unroll
    for (int i = 0; i < 4; i++) {
      int c = i * 512 + t;                      // 0..2047 16B-chunks
      int row = c >> 3, ch = c & 7;
      int col = (ch * 8) ^ ((row & 7) << 3);
      gld_lds16(&A[(size_t)(m0 + row) * CDIM + k0 + col], Ad + c * 16);
      gld_lds16(&Bt[(size_t)(n0 + row) * CDIM + k0 + col], Bd + c * 16);
    }
  };

  STAGE_TILE(0, 0);
  for (int it = 0; it < 16; ++it) {
    if (it + 1 < 16) {
      STAGE_TILE((it + 1) & 1, it + 1);
      asm volatile("s_waitcnt vmcnt(8)" ::: "memory");   // tile it landed
    } else {
      asm volatile("s_waitcnt vmcnt(0)" ::: "memory");
    }
    __builtin_amdgcn_s_barrier();

    const u16* Ar = (const u16*)(smem + (it & 1) * 32768);
    const u16* Br = (const u16*)(smem + 65536 + (it & 1) * 32768);
#pragma unroll
    for (int p = 0; p < 4; p++) {
      const int qm = p >> 1, qn = p & 1;
      bf16x8 af[4][2], bfr[2][2];
#pragma unroll
      for (int mi = 0; mi < 4; mi++)
#pragma unroll
        for (int s = 0; s < 2; s++) {
          int row = wm * 128 + (qm * 4 + mi) * 16 + r16;
          int col = (s * 32 + kg * 8) ^ ((row & 7) << 3);
          af[mi][s] = *(const bf16x8*)&Ar[row * 64 + col];
        }
#pragma unroll
      for (int ni = 0; ni < 2; ni++)
#pragma unroll
        for (int s = 0; s < 2; s++) {
          int row = wn * 64 + (qn * 2 + ni) * 16 + r16;
          int col = (s * 32 + kg * 8) ^ ((row & 7) << 3);
          bfr[ni][s] = *(const bf16x8*)&Br[row * 64 + col];
        }
      __builtin_amdgcn_s_barrier();
      asm volatile("s_waitcnt lgkmcnt(0)" ::: "memory");
      __builtin_amdgcn_sched_barrier(0);
      __builtin_amdgcn_s_setprio(1);
#pragma unroll
      for (int s = 0; s < 2; s++)
#pragma unroll
        for (int mi = 0; mi < 4; mi++)
#pragma unroll
          for (int ni = 0; ni < 2; ni++)
            acc[qm * 4 + mi][qn * 2 + ni] =
                __builtin_amdgcn_mfma_f32_16x16x32_bf16(
                    af[mi][s], bfr[ni][s], acc[qm * 4 + mi][qn * 2 + ni],
                    0, 0, 0);
      __builtin_amdgcn_s_setprio(0);
      __builtin_amdgcn_s_barrier();             // iter-end for p==3
    }
  }
  __syncthreads();   // drain before smem reuse as epilogue bounce buffer

  // epilogue: C/D layout col=lane&15, row=(lane>>4)*4+reg
  u16* Tt = (u16*)smem;                         // [256][256] swizzled
  if (n0 >= 2048) {
    // V: write transposed (row = d-col, col = t), packed b64 writes
#pragma unroll
    for (int m = 0; m < 8; m++)
#pragma unroll
      for (int n = 0; n < 4; n++) {
        int ln = wn * 64 + n * 16 + r16;        // local n (d-ish)
        float bv = bias[n0 + ln];
        int lmb = wm * 128 + m * 16 + kg * 4;   // t base (4 consecutive)
        ushort4 pk;
        pk.x = f2bf(acc[m][n][0] + bv);
        pk.y = f2bf(acc[m][n][1] + bv);
        pk.z = f2bf(acc[m][n][2] + bv);
        pk.w = f2bf(acc[m][n][3] + bv);
        *(ushort4*)&Tt[ln * 256 + (lmb ^ ((ln & 7) << 3))] = pk;
      }
    __syncthreads();
    const int cbase = n0 - 2048;
#pragma unroll
    for (int i = 0; i < 16; i++) {
      int u = i * 512 + t;
      int ln = u >> 5, ch = u & 31;
      u16x8 v = *(const u16x8*)&Tt[ln * 256 + ((ch * 8) ^ ((ln & 7) << 3))];
      int c = cbase + ln, hh = c >> 6, d = c & 63;
      *(u16x8*)&Vt[(((size_t)b * NH + hh) * DH + d) * T_SEQ + tt0 + ch * 8] = v;
    }
  } else {
    // Q/K: row-major bounce, scalar writes, 16B coalesced readback
#pragma unroll
    for (int m = 0; m < 8; m++)
#pragma unroll
      for (int n = 0; n < 4; n++) {
        int ln = wn * 64 + n * 16 + r16;
        float bv = bias[n0 + ln];
#pragma unroll
        for (int reg = 0; reg < 4; reg++) {
          int lm = wm * 128 + m * 16 + kg * 4 + reg;
          Tt[lm * 256 + (ln ^ ((lm & 7) << 3))] = f2bf(acc[m][n][reg] + bv);
        }
      }
    __syncthreads();
    const int cb = n0 & 1023;
    u16* dst = (n0 < 1024) ? Qb : Kb;
#pragma unroll
    for (int i = 0; i < 16; i++) {
      int u = i * 512 + t;
      int row = u >> 5, ch = u & 31;
      u16x8 v = *(const u16x8*)&Tt[row * 256 + ((ch * 8) ^ ((row & 7) << 3))];
      int c = cb + ch * 8, hh = c >> 6, d = c & 63;
      *(u16x8*)&dst[((size_t)(b * NH + hh) * T_SEQ + tt0 + row) * DH + d] = v;
    }
  }
}

// ---------------- proj GEMM (r13-proven 128^2 structure, MODE1 only) ------
__global__ __launch_bounds__(256, 2) void gemm_proj(
    const u16* __restrict__ A, const u16* __restrict__ Bt,
    const float* __restrict__ bias,
    float* __restrict__ Out, const int* __restrict__ lengths, int Kdim) {
  __shared__ u16 SM[16384];
  u16* As = SM;
  u16* Bs = SM + 8192;
  const int t = threadIdx.x;
  const int lane = t & 63, wid = t >> 6;
  const int wr = wid >> 1, wc = wid & 1;
  const int r16 = lane & 15, kg = lane >> 4;
  const int m0 = blockIdx.y * 128, n0 = blockIdx.x * 128;
  const int bb = m0 >> 11, tt0 = m0 & 2047;

  if (tt0 >= lengths[bb]) {                   // fully-padded: zero-fill
    const float4 z4 = make_float4(0.f, 0.f, 0.f, 0.f);
#pragma unroll
    for (int i = 0; i < 16; i++) {
      int u = i * 256 + t;
      int r = u >> 5, c4 = u & 31;
      *(float4*)&Out[(size_t)(m0 + r) * CDIM + n0 + c4 * 4] = z4;
    }
    return;
  }

  f32x4 acc[4][4];
#pragma unroll
  for (int i = 0; i < 4; i++)
#pragma unroll
    for (int j = 0; j < 4; j++) acc[i][j] = (f32x4){0.f, 0.f, 0.f, 0.f};

  for (int k0 = 0; k0 < Kdim; k0 += 64) {
#pragma unroll
    for (int i = 0; i < 4; i++) {
      int idx = i * 256 + t;
      int row = idx >> 3;
      int chunk = idx & 7;
      int colel = (chunk * 8) ^ ((row & 7) << 3);
      gld_lds16(&A[(size_t)(m0 + row) * Kdim + k0 + colel], &As[idx * 8]);
      gld_lds16(&Bt[(size_t)(n0 + row) * Kdim + k0 + colel], &Bs[idx * 8]);
    }
    __syncthreads();

#pragma unroll
    for (int s = 0; s < 2; s++) {
      bf16x8 af[4], bfr[4];
#pragma unroll
      for (int m = 0; m < 4; m++) {
        int row = wr * 64 + m * 16 + r16;
        int colel = (s * 32 + kg * 8) ^ ((row & 7) << 3);
        af[m] = *(const bf16x8*)&As[row * 64 + colel];
      }
#pragma unroll
      for (int n = 0; n < 4; n++) {
        int row = wc * 64 + n * 16 + r16;
        int colel = (s * 32 + kg * 8) ^ ((row & 7) << 3);
        bfr[n] = *(const bf16x8*)&Bs[row * 64 + colel];
      }
#pragma unroll
      for (int m = 0; m < 4; m++)
#pragma unroll
        for (int n = 0; n < 4; n++)
          acc[m][n] = __builtin_amdgcn_mfma_f32_16x16x32_bf16(
              af[m], bfr[n], acc[m][n], 0, 0, 0);
    }
    __syncthreads();
  }

#pragma unroll
  for (int m = 0; m < 4; m++) {
    int gmb = m0 + wr * 64 + m * 16 + kg * 4;
#pragma unroll
    for (int n = 0; n < 4; n++) {
      int gn = n0 + wc * 64 + n * 16 + r16;
      float bv = bias[gn];
#pragma unroll
      for (int reg = 0; reg < 4; reg++) {
        float v = acc[m][n][reg] + bv;
        int row = gmb + reg;
        int b = row >> 11, tt = row & 2047;
        if (tt >= lengths[b]) v = 0.f;
        Out[(size_t)row * CDIM + gn] = v;
      }
    }
  }
}

// ---------------- flash attention (r13-proven, 121 us) -------------------
__global__ __launch_bounds__(256) void attn32p_kernel(
    const u16* __restrict__ Qb, const u16* __restrict__ Kb,
    const u16* __restrict__ Vt, u16* __restrict__ yb,
    const int* __restrict__ lengths) {
  __shared__ __attribute__((aligned(16))) char smem[65536];  // 4 x (8K K + 8K V)
  const int t = threadIdx.x, lane = t & 63, wid = t >> 6;
  const int l31 = lane & 31, hi = lane >> 5;
  const int bh = blockIdx.y, b = bh >> 4, h = bh & (NH - 1);
  const int len = lengths[b];
  const int nAct = (len + 127) >> 7;
  const int npairs = (nAct + 1) >> 1;
  const int iq = blockIdx.x;
  if (iq >= npairs) return;
  const int q0L = iq * 128;
  const int q0H = (nAct - 1 - iq) * 128;
  const bool hiAct = q0H > q0L;
  const int q0Lw = q0L + wid * 32, q0Hw = q0H + wid * 32;
  const int qrowL = q0Lw + l31, qrowH = q0Hw + l31;
  const u16* Qh = Qb + (size_t)bh * T_SEQ * DH;
  const u16* Kh = Kb + (size_t)bh * T_SEQ * DH;
  const u16* Vth = Vt + (size_t)bh * DH * T_SEQ;
  const float SC = 0.18033688011112042f;
  const float THR = 44.3614195558365f;

  const int lenceil = (len + 63) & ~63;
  const int kvH = (q0H + 128 < lenceil) ? q0H + 128 : lenceil;
  const int kvL = (q0L + 128 < lenceil) ? q0L + 128 : lenceil;
  const int kv_end = hiAct ? kvH : kvL;
  const int ntiles = kv_end >> 6;

  bf16x8 qfL[4], qfH[4];
#pragma unroll
  for (int ks = 0; ks < 4; ks++) {
    qfL[ks] = *(const bf16x8*)&Qh[(size_t)qrowL * DH + ks * 16 + hi * 8];
    qfH[ks] = *(const bf16x8*)&Qh[(size_t)qrowH * DH + ks * 16 + hi * 8];
  }

  f32x16 oaccL[2], oaccH[2];
  oaccL[0] = (f32x16)0.f; oaccL[1] = (f32x16)0.f;
  oaccH[0] = (f32x16)0.f; oaccH[1] = (f32x16)0.f;
  float mL = NEGBIG, lL = 0.f, mH = NEGBIG, lH = 0.f;

  const int idx0 = t, idx1 = 256 + t;
  const int row0 = idx0 >> 3, ch0 = idx0 & 7;
  const int row1 = idx1 >> 3, ch1 = idx1 & 7;
  const int kc0 = (ch0 * 8) ^ ((row0 & 7) << 3);
  const int kc1 = (ch1 * 8) ^ ((row1 & 7) << 3);
  const char* kp0 = (const char*)Kh + ((size_t)row0 * DH + kc0) * 2;
  const char* kp1 = (const char*)Kh + ((size_t)row1 * DH + kc1) * 2;
  const char* vp0 = (const char*)Vth + ((size_t)row0 * T_SEQ + kc0) * 2;
  const char* vp1 = (const char*)Vth + ((size_t)row1 * T_SEQ + kc1) * 2;

  auto STAGE = [&](int bsel) {
    char* base = smem + bsel * 16384;
    gld_lds16(kp0, base + idx0 * 16);
    gld_lds16(kp1, base + idx1 * 16);
    gld_lds16(vp0, base + 8192 + idx0 * 16);
    gld_lds16(vp1, base + 8192 + idx1 * 16);
    kp0 += 8192; kp1 += 8192; vp0 += 128; vp1 += 128;
  };

  auto FLASH = [&](const u16* Ks, const u16* Vts, int kv0, int q0w, int qrow,
                   bf16x8* qf, f32x16* oacc, float& mrun, float& lrun) {
    f32x16 sacc[2];
    sacc[0] = (f32x16)0.f; sacc[1] = (f32x16)0.f;
#pragma unroll
    for (int kb = 0; kb < 2; kb++)
#pragma unroll
      for (int ks = 0; ks < 4; ks++) {
        int row = kb * 32 + l31;
        int col = (ks * 16 + hi * 8) ^ ((row & 7) << 3);
        bf16x8 ak = *(const bf16x8*)&Ks[row * 64 + col];
        sacc[kb] = __builtin_amdgcn_mfma_f32_32x32x16_bf16(
            ak, qf[ks], sacc[kb], 0, 0, 0);
      }

    if ((kv0 + 63 > q0w) || (kv0 + 64 > len)) {
#pragma unroll
      for (int kb = 0; kb < 2; kb++)
#pragma unroll
        for (int r = 0; r < 16; r++) {
          int key = kv0 + kb * 32 + (r & 3) + 8 * (r >> 2) + 4 * hi;
          if (key > qrow || key >= len) sacc[kb][r] = NEGBIG;
        }
    }
    float tm[16];
#pragma unroll
    for (int r = 0; r < 16; r++) tm[r] = fmaxf(sacc[0][r], sacc[1][r]);
#pragma unroll
    for (int r = 0; r < 8; r++) tm[r] = fmaxf(tm[r], tm[r + 8]);
#pragma unroll
    for (int r = 0; r < 4; r++) tm[r] = fmaxf(tm[r], tm[r + 4]);
    tm[0] = fmaxf(fmaxf(tm[0], tm[2]), fmaxf(tm[1], tm[3]));
    float mt = fmaxf(tm[0], __shfl_xor(tm[0], 32));

    if (!__all(mt <= mrun + THR)) {
      float mnew = fmaxf(mrun, mt);
      float fac = exp2f((mrun - mnew) * SC);
      mrun = mnew;
      lrun *= fac;
#pragma unroll
      for (int r = 0; r < 16; r++) { oacc[0][r] *= fac; oacc[1][r] *= fac; }
    }
    const float msc = mrun * SC;
#pragma unroll
    for (int kb = 0; kb < 2; kb++)
#pragma unroll
      for (int r = 0; r < 16; r++)
        sacc[kb][r] = exp2f(fmaf(sacc[kb][r], SC, -msc));
    float pt[16];
#pragma unroll
    for (int r = 0; r < 16; r++) pt[r] = sacc[0][r] + sacc[1][r];
#pragma unroll
    for (int r = 0; r < 8; r++) pt[r] += pt[r + 8];
#pragma unroll
    for (int r = 0; r < 4; r++) pt[r] += pt[r + 4];
    float ps = (pt[0] + pt[2]) + (pt[1] + pt[3]);
    ps += __shfl_xor(ps, 32);
    lrun += ps;

#pragma unroll
    for (int ks = 0; ks < 4; ks++) {
      const int kb = ks >> 1, rb = (ks & 1) * 8;
      uint32_t d0, d1, d2, d3;
      asm("v_cvt_pk_bf16_f32 %0, %1, %2" : "=v"(d0)
          : "v"(sacc[kb][rb + 0]), "v"(sacc[kb][rb + 1]));
      asm("v_cvt_pk_bf16_f32 %0, %1, %2" : "=v"(d1)
          : "v"(sacc[kb][rb + 2]), "v"(sacc[kb][rb + 3]));
      asm("v_cvt_pk_bf16_f32 %0, %1, %2" : "=v"(d2)
          : "v"(sacc[kb][rb + 4]), "v"(sacc[kb][rb + 5]));
      asm("v_cvt_pk_bf16_f32 %0, %1, %2" : "=v"(d3)
          : "v"(sacc[kb][rb + 6]), "v"(sacc[kb][rb + 7]));
      bf16x8 pb = __builtin_bit_cast(bf16x8, (u32x4){d0, d1, d2, d3});
#pragma unroll
      for (int mb = 0; mb < 2; mb++) {
        int row = mb * 32 + l31;
        int sw = (row & 7);
        bf16x4 v1 = *(const bf16x4*)&Vts[row * 64 + ((2 * ks) ^ sw) * 8 + 4 * hi];
        bf16x4 v2 = *(const bf16x4*)&Vts[row * 64 + ((2 * ks + 1) ^ sw) * 8 + 4 * hi];
        bf16x8 av;
#pragma unroll
        for (int j = 0; j < 4; j++) { av[j] = v1[j]; av[4 + j] = v2[j]; }
        oacc[mb] = __builtin_amdgcn_mfma_f32_32x32x16_bf16(
            av, pb, oacc[mb], 0, 0, 0);
      }
    }
  };

  STAGE(0); STAGE(1);
  for (int it = 0; it < ntiles; ++it) {
    if (it + 2 < ntiles) STAGE((it + 2) & 3);
    const int r = ntiles - 1 - it;
    if (r >= 2)      asm volatile("s_waitcnt vmcnt(8)" ::: "memory");
    else if (r == 1) asm volatile("s_waitcnt vmcnt(4)" ::: "memory");
    else             asm volatile("s_waitcnt vmcnt(0)" ::: "memory");
    __builtin_amdgcn_s_barrier();
    __builtin_amdgcn_sched_barrier(0);

    const u16* Ks  = (const u16*)(smem + (it & 3) * 16384);
    const u16* Vts = (const u16*)(smem + (it & 3) * 16384 + 8192);
    const int kv0 = it << 6;
    if (hiAct && kv0 <= q0Hw + 31)
      FLASH(Ks, Vts, kv0, q0Hw, qrowH, qfH, oaccH, mH, lH);
    if (kv0 <= q0Lw + 31)
      FLASH(Ks, Vts, kv0, q0Lw, qrowL, qfL, oaccL, mL, lL);
  }
  __syncthreads();

  u16* yt = (u16*)smem + wid * (32 * 72);
  auto EPI = [&](f32x16* oacc, float lrun, int q0w) {
    const float inv = (lrun > 0.f) ? 1.f / lrun : 0.f;
#pragma unroll
    for (int mb = 0; mb < 2; mb++)
#pragma unroll
      for (int r = 0; r < 16; r += 2) {
        int d = mb * 32 + (r & 3) + 8 * (r >> 2) + 4 * hi;
        float a0 = oacc[mb][r] * inv, a1 = oacc[mb][r + 1] * inv;
        uint32_t pw;
        asm("v_cvt_pk_bf16_f32 %0, %1, %2" : "=v"(pw) : "v"(a0), "v"(a1));
        *(uint32_t*)&yt[l31 * 72 + d] = pw;
      }
    asm volatile("s_waitcnt lgkmcnt(0)" ::: "memory");
    __builtin_amdgcn_sched_barrier(0);
#pragma unroll
    for (int pass = 0; pass < 4; pass++) {
      int rowq = pass * 8 + (lane >> 3);
      int col8 = (lane & 7) * 8;
      u16x8 v = *(const u16x8*)&yt[rowq * 72 + col8];
      *(u16x8*)&yb[((size_t)b * T_SEQ + q0w + rowq) * CDIM + h * DH + col8] = v;
    }
    asm volatile("s_waitcnt lgkmcnt(0)" ::: "memory");
    __builtin_amdgcn_sched_barrier(0);
  };
  EPI(oaccL, lL, q0Lw);
  if (hiAct) EPI(oaccH, lH, q0Hw);
}

// ---------------- launch ----------------
extern "C" void kernel_launch(void* const* d_in, const int* in_sizes, int n_in,
                              void* d_out, int out_size, void* d_ws, size_t ws_size,
                              hipStream_t stream) {
  const float* x  = (const float*)d_in[0];
  const void*  mask = d_in[1];
  const float* Wa = (const float*)d_in[2];
  const float* ba = (const float*)d_in[3];
  const float* Wp = (const float*)d_in[4];
  const float* bp = (const float*)d_in[5];
  float* out = (float*)d_out;

  char* w = (char*)d_ws;
  u16* xb  = (u16*)w; w += (size_t)MROWS * CDIM * 2;   // 16 MB (reused as yb)
  u16* WaT = (u16*)w; w += (size_t)N3 * CDIM * 2;      // 6 MB
  u16* WpT = (u16*)w; w += (size_t)CDIM * CDIM * 2;    // 2 MB
  u16* Qb  = (u16*)w; w += (size_t)MROWS * CDIM * 2;   // 16 MB
  u16* Kb  = (u16*)w; w += (size_t)MROWS * CDIM * 2;   // 16 MB
  u16* Vt  = (u16*)w; w += (size_t)MROWS * CDIM * 2;   // 16 MB  [b,h,d,t]
  int* lengths = (int*)w;                               // 16 B
  u16* yb = xb;  // alias: xb dead after QKV GEMM

  cvt_f32_bf16<<<(MROWS * CDIM / 4 + 255) / 256, 256, 0, stream>>>(x, xb, MROWS * CDIM);
  wt_tiled<<<dim3(N3 / 64, CDIM / 64), 256, 0, stream>>>(Wa, WaT, CDIM, N3);
  wt_tiled<<<dim3(CDIM / 64, CDIM / 64), 256, 0, stream>>>(Wp, WpT, CDIM, CDIM);
  len_kernel<<<BATCH, 256, 0, stream>>>(mask, lengths);

  gemm256_qkv<<<dim3(N3 / 256, MROWS / 256), 512, 0, stream>>>(
      xb, WaT, ba, Qb, Kb, Vt, lengths);

  attn32p_kernel<<<dim3(8, BATCH * NH), 256, 0, stream>>>(
      Qb, Kb, Vt, yb, lengths);

  gemm_proj<<<dim3(CDIM / 128, MROWS / 128), 256, 0, stream>>>(
      yb, WpT, bp, out, lengths, CDIM);
}

// Round 15
// 230.819 us; speedup vs baseline: 1.0462x; 1.0462x over previous
//
#include <hip/hip_runtime.h>
#include <stdint.h>

// Problem constants (B=4, T=2048, C=1024, H=16, D=64)
#define T_SEQ 2048
#define CDIM  1024
#define NH    16
#define DH    64
#define BATCH 4
#define MROWS (BATCH * T_SEQ)   // 8192
#define N3    (3 * CDIM)        // 3072
#define NEGBIG -1e30f

typedef unsigned short u16;
typedef __attribute__((ext_vector_type(8))) __bf16 bf16x8;
typedef __attribute__((ext_vector_type(4))) __bf16 bf16x4;
typedef __attribute__((ext_vector_type(8))) unsigned short u16x8;
typedef __attribute__((ext_vector_type(4))) float f32x4;
typedef __attribute__((ext_vector_type(16))) float f32x16;
typedef __attribute__((ext_vector_type(4))) unsigned int u32x4;

__device__ inline u16 f2bf(float f) {
  uint32_t u = __builtin_bit_cast(uint32_t, f);
  u += 0x7FFFu + ((u >> 16) & 1u);   // RNE; inputs finite
  return (u16)(u >> 16);
}

// async global->LDS, 16B per lane; LDS dest = wave-uniform base + lane*16
__device__ inline void gld_lds16(const void* g, void* l) {
  __builtin_amdgcn_global_load_lds(
      (const __attribute__((address_space(1))) void*)g,
      (__attribute__((address_space(3))) void*)l, 16, 0, 0);
}

// ---------------- aux kernels ----------------

__global__ __launch_bounds__(256) void cvt_f32_bf16(
    const float* __restrict__ in, u16* __restrict__ out, int n) {
  int i = (blockIdx.x * 256 + threadIdx.x) * 4;
  if (i >= n) return;
  float4 v = *(const float4*)&in[i];
  ushort4 o; o.x = f2bf(v.x); o.y = f2bf(v.y); o.z = f2bf(v.z); o.w = f2bf(v.w);
  *(ushort4*)&out[i] = o;
}

// W [K][N] fp32 -> WT [N][K] bf16, LDS-tiled (coalesced both sides)
__global__ __launch_bounds__(256) void wt_tiled(
    const float* __restrict__ W, u16* __restrict__ WT, int K, int N) {
  __shared__ float tile[64][65];
  const int k0 = blockIdx.y * 64, n0 = blockIdx.x * 64;
  const int t = threadIdx.x, cr = t >> 6, cc = t & 63;
#pragma unroll
  for (int i = 0; i < 16; i++) {
    int r = i * 4 + cr;
    tile[r][cc] = W[(size_t)(k0 + r) * N + n0 + cc];
  }
  __syncthreads();
#pragma unroll
  for (int i = 0; i < 16; i++) {
    int r = i * 4 + cr;  // output row (n)
    WT[(size_t)(n0 + r) * K + k0 + cc] = f2bf(tile[cc][r]);
  }
}

// lengths[b] = count of non-padded rows; auto-detect int32 vs byte mask.
__global__ __launch_bounds__(256) void len_kernel(
    const void* __restrict__ maskp, int* __restrict__ lengths) {
  __shared__ int flag;
  __shared__ int red[256];
  const int t = threadIdx.x, b = blockIdx.x;
  if (t == 0) flag = 0;
  __syncthreads();
  const uint32_t* mw = (const uint32_t*)maskp;
  int f = 0;
  for (int i = t; i < 2048; i += 256) f |= (mw[i] > 1u) ? 1 : 0;
  if (f) atomicOr(&flag, 1);
  __syncthreads();
  int cnt = 0;
  if (flag) {
    const uint8_t* mb = (const uint8_t*)maskp;
    for (int i = t; i < T_SEQ; i += 256) cnt += (mb[(size_t)b * T_SEQ + i] == 0);
  } else {
    const int* mi = (const int*)maskp;
    for (int i = t; i < T_SEQ; i += 256) cnt += (mi[(size_t)b * T_SEQ + i] == 0);
  }
  red[t] = cnt;
  __syncthreads();
  for (int s = 128; s > 0; s >>= 1) {
    if (t < s) red[t] += red[t + s];
    __syncthreads();
  }
  if (t == 0) lengths[b] = red[0];
}

// ---------------- GEMM: C[M,N] = A[M,K] * Bt[N,K]^T + bias ----------------
// r13-PROVEN 128x128 tile, BK=64, 4 waves, mfma_f32_16x16x32_bf16, XOR-
// swizzled LDS. Padded-row skip. MODE 0: n<2048 -> Q/K via LDS bounce;
// n>=2048 -> V transposed to Vt [b,h,d,t]. MODE 1: fp32 out + zeroing.
template <int MODE>
__global__ __launch_bounds__(256, 2) void gemm_bf16(
    const u16* __restrict__ A, const u16* __restrict__ Bt,
    const float* __restrict__ bias,
    u16* __restrict__ Qb, u16* __restrict__ Kb, u16* __restrict__ Vt,
    float* __restrict__ Out, const int* __restrict__ lengths,
    int Mdim, int Ndim, int Kdim) {
  __shared__ u16 SM[16384];           // As = SM[0:8192], Bs = SM[8192:16384]
  u16* As = SM;
  u16* Bs = SM + 8192;
  const int t = threadIdx.x;
  const int lane = t & 63, wid = t >> 6;
  const int wr = wid >> 1, wc = wid & 1;
  const int r16 = lane & 15, kg = lane >> 4;
  const int m0 = blockIdx.y * 128, n0 = blockIdx.x * 128;
  const int bb = m0 >> 11, tt0 = m0 & 2047;   // batch, within-batch t offset

  if (tt0 >= lengths[bb]) {                   // fully-padded M-tile (uniform)
    if (MODE == 1) {
      const float4 z4 = make_float4(0.f, 0.f, 0.f, 0.f);
#pragma unroll
      for (int i = 0; i < 16; i++) {
        int u = i * 256 + t;
        int r = u >> 5, c4 = u & 31;
        *(float4*)&Out[(size_t)(m0 + r) * CDIM + n0 + c4 * 4] = z4;
      }
    }
    return;
  }

  f32x4 acc[4][4];
#pragma unroll
  for (int i = 0; i < 4; i++)
#pragma unroll
    for (int j = 0; j < 4; j++) acc[i][j] = (f32x4){0.f, 0.f, 0.f, 0.f};

  for (int k0 = 0; k0 < Kdim; k0 += 64) {
#pragma unroll
    for (int i = 0; i < 4; i++) {
      int idx = i * 256 + t;           // 0..1023
      int row = idx >> 3;              // 0..127
      int chunk = idx & 7;
      int colel = (chunk * 8) ^ ((row & 7) << 3);
      gld_lds16(&A[(size_t)(m0 + row) * Kdim + k0 + colel], &As[idx * 8]);
      gld_lds16(&Bt[(size_t)(n0 + row) * Kdim + k0 + colel], &Bs[idx * 8]);
    }
    __syncthreads();

#pragma unroll
    for (int s = 0; s < 2; s++) {
      bf16x8 af[4], bfr[4];
#pragma unroll
      for (int m = 0; m < 4; m++) {
        int row = wr * 64 + m * 16 + r16;
        int colel = (s * 32 + kg * 8) ^ ((row & 7) << 3);
        af[m] = *(const bf16x8*)&As[row * 64 + colel];
      }
#pragma unroll
      for (int n = 0; n < 4; n++) {
        int row = wc * 64 + n * 16 + r16;
        int colel = (s * 32 + kg * 8) ^ ((row & 7) << 3);
        bfr[n] = *(const bf16x8*)&Bs[row * 64 + colel];
      }
#pragma unroll
      for (int m = 0; m < 4; m++)
#pragma unroll
        for (int n = 0; n < 4; n++)
          acc[m][n] = __builtin_amdgcn_mfma_f32_16x16x32_bf16(
              af[m], bfr[n], acc[m][n], 0, 0, 0);
    }
    __syncthreads();
  }

  // epilogue: C/D layout col=lane&15, row=(lane>>4)*4+reg
  if (MODE == 0) {
    const int b = bb;
    if (n0 >= 2048) {
      u16* Tt = SM;  // [128][128], chunk-swizzled
#pragma unroll
      for (int m = 0; m < 4; m++)
#pragma unroll
        for (int n = 0; n < 4; n++) {
          int ln = wc * 64 + n * 16 + r16;
          float bv = bias[n0 + ln];
#pragma unroll
          for (int reg = 0; reg < 4; reg++) {
            int lm = wr * 64 + m * 16 + kg * 4 + reg;
            Tt[ln * 128 + (lm ^ ((ln & 7) << 3))] = f2bf(acc[m][n][reg] + bv);
          }
        }
      __syncthreads();
      const int cbase = n0 - 2048;
#pragma unroll
      for (int i = 0; i < 8; i++) {
        int u = i * 256 + t;
        int ln = u >> 4, ch = u & 15;
        u16x8 v = *(const u16x8*)&Tt[ln * 128 + ((ch * 8) ^ ((ln & 7) << 3))];
        int c = cbase + ln, hh = c >> 6, d = c & 63;
        *(u16x8*)&Vt[(((size_t)b * NH + hh) * DH + d) * T_SEQ + tt0 + ch * 8] = v;
      }
    } else {
      u16* Tt = SM;  // [128 t-rows][128 n-cols], col-swizzled per row
#pragma unroll
      for (int m = 0; m < 4; m++)
#pragma unroll
        for (int n = 0; n < 4; n++) {
          int ln = wc * 64 + n * 16 + r16;
          float bv = bias[n0 + ln];
#pragma unroll
          for (int reg = 0; reg < 4; reg++) {
            int lm = wr * 64 + m * 16 + kg * 4 + reg;
            Tt[lm * 128 + (ln ^ ((lm & 7) << 3))] = f2bf(acc[m][n][reg] + bv);
          }
        }
      __syncthreads();
      const int cb = n0 & 1023;
      u16* dst = (n0 < 1024) ? Qb : Kb;
#pragma unroll
      for (int i = 0; i < 8; i++) {
        int u = i * 256 + t;
        int row = u >> 4, ch = u & 15;
        u16x8 v = *(const u16x8*)&Tt[row * 128 + ((ch * 8) ^ ((row & 7) << 3))];
        int c = cb + ch * 8, hh = c >> 6, d = c & 63;
        *(u16x8*)&dst[((size_t)(b * NH + hh) * T_SEQ + tt0 + row) * DH + d] = v;
      }
    }
    return;
  }

#pragma unroll
  for (int m = 0; m < 4; m++) {
    int gmb = m0 + wr * 64 + m * 16 + kg * 4;
#pragma unroll
    for (int n = 0; n < 4; n++) {
      int gn = n0 + wc * 64 + n * 16 + r16;
      float bv = bias[gn];
#pragma unroll
      for (int reg = 0; reg < 4; reg++) {
        float v = acc[m][n][reg] + bv;
        int row = gmb + reg;           // = b*T + t
        int b = row >> 11, tt = row & 2047;
        if (tt >= lengths[b]) v = 0.f;
        Out[(size_t)row * CDIM + gn] = v;
      }
    }
  }
}

// ---------------- flash attention, length-aware pairs, RING-3 ------------
// r13-proven body (121 us) with ONE delta: ring-3 LDS (48KB -> 3 blocks/CU,
// was 64KB/2). Schedule per iter (STAGE moved AFTER the barrier — the safe
// ring-3 form): {wait vmcnt(4|0); s_barrier; sched_barrier; STAGE((it+2)%3);
// FLASH(it%3)}. Writer of buf (it+2)%3 ≡ (it-1)%3 issues after the iter-it
// barrier; its last readers (compute it-1) are pre-barrier -> race-free.
// vmcnt: at iter top outstanding = tile it (4) + tile it+1 (4) -> vmcnt(4)
// drains tile it; last iter drains to 0.
__global__ __launch_bounds__(256) void attn32p_kernel(
    const u16* __restrict__ Qb, const u16* __restrict__ Kb,
    const u16* __restrict__ Vt, u16* __restrict__ yb,
    const int* __restrict__ lengths) {
  __shared__ __attribute__((aligned(16))) char smem[49152];  // 3 x (8K K + 8K V)
  const int t = threadIdx.x, lane = t & 63, wid = t >> 6;
  const int l31 = lane & 31, hi = lane >> 5;
  const int bh = blockIdx.y, b = bh >> 4, h = bh & (NH - 1);
  const int len = lengths[b];
  const int nAct = (len + 127) >> 7;         // active q-tiles (8..16)
  const int npairs = (nAct + 1) >> 1;
  const int iq = blockIdx.x;                 // 0..7
  if (iq >= npairs) return;                  // uniform, before any barrier
  const int q0L = iq * 128;
  const int q0H = (nAct - 1 - iq) * 128;
  const bool hiAct = q0H > q0L;              // middle tile pairs with itself
  const int q0Lw = q0L + wid * 32, q0Hw = q0H + wid * 32;
  const int qrowL = q0Lw + l31, qrowH = q0Hw + l31;
  const u16* Qh = Qb + (size_t)bh * T_SEQ * DH;
  const u16* Kh = Kb + (size_t)bh * T_SEQ * DH;
  const u16* Vth = Vt + (size_t)bh * DH * T_SEQ;
  const float SC = 0.18033688011112042f;     // log2(e) / sqrt(64)
  const float THR = 44.3614195558365f;       // 8 / SC (raw-domain defer thr)

  const int lenceil = (len + 63) & ~63;
  const int kvH = (q0H + 128 < lenceil) ? q0H + 128 : lenceil;
  const int kvL = (q0L + 128 < lenceil) ? q0L + 128 : lenceil;
  const int kv_end = hiAct ? kvH : kvL;
  const int ntiles = kv_end >> 6;            // >= 2 always

  // Q B-fragments for both tiles: B[n=q=l31][k=d=ks*16+hi*8+i]
  bf16x8 qfL[4], qfH[4];
#pragma unroll
  for (int ks = 0; ks < 4; ks++) {
    qfL[ks] = *(const bf16x8*)&Qh[(size_t)qrowL * DH + ks * 16 + hi * 8];
    qfH[ks] = *(const bf16x8*)&Qh[(size_t)qrowH * DH + ks * 16 + hi * 8];
  }

  f32x16 oaccL[2], oaccH[2];
  oaccL[0] = (f32x16)0.f; oaccL[1] = (f32x16)0.f;
  oaccH[0] = (f32x16)0.f; oaccH[1] = (f32x16)0.f;
  float mL = NEGBIG, lL = 0.f, mH = NEGBIG, lH = 0.f;

  // per-lane staging sources (running ptrs; K +8192B/tile, V +128B/tile)
  const int idx0 = t, idx1 = 256 + t;
  const int row0 = idx0 >> 3, ch0 = idx0 & 7;
  const int row1 = idx1 >> 3, ch1 = idx1 & 7;
  const int kc0 = (ch0 * 8) ^ ((row0 & 7) << 3);
  const int kc1 = (ch1 * 8) ^ ((row1 & 7) << 3);
  const char* kp0 = (const char*)Kh + ((size_t)row0 * DH + kc0) * 2;
  const char* kp1 = (const char*)Kh + ((size_t)row1 * DH + kc1) * 2;
  const char* vp0 = (const char*)Vth + ((size_t)row0 * T_SEQ + kc0) * 2;
  const char* vp1 = (const char*)Vth + ((size_t)row1 * T_SEQ + kc1) * 2;

  auto STAGE = [&](int bsel) {               // 4 vm-ops per thread
    char* base = smem + bsel * 16384;
    gld_lds16(kp0, base + idx0 * 16);
    gld_lds16(kp1, base + idx1 * 16);
    gld_lds16(vp0, base + 8192 + idx0 * 16);
    gld_lds16(vp1, base + 8192 + idx1 * 16);
    kp0 += 8192; kp1 += 8192; vp0 += 128; vp1 += 128;
  };

  // one flash step for one q-tile on the staged (Ks,Vts) KV tile
  auto FLASH = [&](const u16* Ks, const u16* Vts, int kv0, int q0w, int qrow,
                   bf16x8* qf, f32x16* oacc, float& mrun, float& lrun) {
    f32x16 sacc[2];
    sacc[0] = (f32x16)0.f; sacc[1] = (f32x16)0.f;
#pragma unroll
    for (int kb = 0; kb < 2; kb++)
#pragma unroll
      for (int ks = 0; ks < 4; ks++) {
        int row = kb * 32 + l31;
        int col = (ks * 16 + hi * 8) ^ ((row & 7) << 3);
        bf16x8 ak = *(const bf16x8*)&Ks[row * 64 + col];
        sacc[kb] = __builtin_amdgcn_mfma_f32_32x32x16_bf16(
            ak, qf[ks], sacc[kb], 0, 0, 0);
      }

    if ((kv0 + 63 > q0w) || (kv0 + 64 > len)) {   // mask (raw domain)
#pragma unroll
      for (int kb = 0; kb < 2; kb++)
#pragma unroll
        for (int r = 0; r < 16; r++) {
          int key = kv0 + kb * 32 + (r & 3) + 8 * (r >> 2) + 4 * hi;
          if (key > qrow || key >= len) sacc[kb][r] = NEGBIG;
        }
    }
    // tree max (depth 5) + cross-half shfl
    float tm[16];
#pragma unroll
    for (int r = 0; r < 16; r++) tm[r] = fmaxf(sacc[0][r], sacc[1][r]);
#pragma unroll
    for (int r = 0; r < 8; r++) tm[r] = fmaxf(tm[r], tm[r + 8]);
#pragma unroll
    for (int r = 0; r < 4; r++) tm[r] = fmaxf(tm[r], tm[r + 4]);
    tm[0] = fmaxf(fmaxf(tm[0], tm[2]), fmaxf(tm[1], tm[3]));
    float mt = fmaxf(tm[0], __shfl_xor(tm[0], 32));

    if (!__all(mt <= mrun + THR)) {          // defer-max (T13)
      float mnew = fmaxf(mrun, mt);
      float fac = exp2f((mrun - mnew) * SC);
      mrun = mnew;
      lrun *= fac;
#pragma unroll
      for (int r = 0; r < 16; r++) { oacc[0][r] *= fac; oacc[1][r] *= fac; }
    }
    const float msc = mrun * SC;
#pragma unroll
    for (int kb = 0; kb < 2; kb++)
#pragma unroll
      for (int r = 0; r < 16; r++)
        sacc[kb][r] = exp2f(fmaf(sacc[kb][r], SC, -msc));
    float pt[16];
#pragma unroll
    for (int r = 0; r < 16; r++) pt[r] = sacc[0][r] + sacc[1][r];
#pragma unroll
    for (int r = 0; r < 8; r++) pt[r] += pt[r + 8];
#pragma unroll
    for (int r = 0; r < 4; r++) pt[r] += pt[r + 4];
    float ps = (pt[0] + pt[2]) + (pt[1] + pt[3]);
    ps += __shfl_xor(ps, 32);
    lrun += ps;

    // O^T += V^T * P^T (slot-permuted, zero cross-lane traffic)
#pragma unroll
    for (int ks = 0; ks < 4; ks++) {
      const int kb = ks >> 1, rb = (ks & 1) * 8;
      uint32_t d0, d1, d2, d3;
      asm("v_cvt_pk_bf16_f32 %0, %1, %2" : "=v"(d0)
          : "v"(sacc[kb][rb + 0]), "v"(sacc[kb][rb + 1]));
      asm("v_cvt_pk_bf16_f32 %0, %1, %2" : "=v"(d1)
          : "v"(sacc[kb][rb + 2]), "v"(sacc[kb][rb + 3]));
      asm("v_cvt_pk_bf16_f32 %0, %1, %2" : "=v"(d2)
          : "v"(sacc[kb][rb + 4]), "v"(sacc[kb][rb + 5]));
      asm("v_cvt_pk_bf16_f32 %0, %1, %2" : "=v"(d3)
          : "v"(sacc[kb][rb + 6]), "v"(sacc[kb][rb + 7]));
      bf16x8 pb = __builtin_bit_cast(bf16x8, (u32x4){d0, d1, d2, d3});
#pragma unroll
      for (int mb = 0; mb < 2; mb++) {
        int row = mb * 32 + l31;
        int sw = (row & 7);
        bf16x4 v1 = *(const bf16x4*)&Vts[row * 64 + ((2 * ks) ^ sw) * 8 + 4 * hi];
        bf16x4 v2 = *(const bf16x4*)&Vts[row * 64 + ((2 * ks + 1) ^ sw) * 8 + 4 * hi];
        bf16x8 av;
#pragma unroll
        for (int j = 0; j < 4; j++) { av[j] = v1[j]; av[4 + j] = v2[j]; }
        oacc[mb] = __builtin_amdgcn_mfma_f32_32x32x16_bf16(
            av, pb, oacc[mb], 0, 0, 0);
      }
    }
  };

  // ring-3, 1 barrier/iter, STAGE after barrier (safe form; see header)
  STAGE(0); STAGE(1);
  int bufc = 0;                                // it % 3
  for (int it = 0; it < ntiles; ++it) {
    if (it + 1 < ntiles) asm volatile("s_waitcnt vmcnt(4)" ::: "memory");
    else                 asm volatile("s_waitcnt vmcnt(0)" ::: "memory");
    __builtin_amdgcn_s_barrier();
    __builtin_amdgcn_sched_barrier(0);
    if (it + 2 < ntiles) {
      int st = bufc + 2; if (st >= 3) st -= 3;
      STAGE(st);
    }

    const u16* Ks  = (const u16*)(smem + bufc * 16384);
    const u16* Vts = (const u16*)(smem + bufc * 16384 + 8192);
    const int kv0 = it << 6;
    if (hiAct && kv0 <= q0Hw + 31)
      FLASH(Ks, Vts, kv0, q0Hw, qrowH, qfH, oaccH, mH, lH);
    if (kv0 <= q0Lw + 31)
      FLASH(Ks, Vts, kv0, q0Lw, qrowL, qfL, oaccL, mL, lL);
    bufc = (bufc == 2) ? 0 : bufc + 1;
  }
  __syncthreads();  // all compute done before smem reuse as epilogue buffer

  // epilogue: O^T regs -> per-wave LDS [32 q][72 d] -> coalesced global
  u16* yt = (u16*)smem + wid * (32 * 72);
  auto EPI = [&](f32x16* oacc, float lrun, int q0w) {
    const float inv = (lrun > 0.f) ? 1.f / lrun : 0.f;
#pragma unroll
    for (int mb = 0; mb < 2; mb++)
#pragma unroll
      for (int r = 0; r < 16; r += 2) {
        int d = mb * 32 + (r & 3) + 8 * (r >> 2) + 4 * hi;
        float a0 = oacc[mb][r] * inv, a1 = oacc[mb][r + 1] * inv;
        uint32_t pw;
        asm("v_cvt_pk_bf16_f32 %0, %1, %2" : "=v"(pw) : "v"(a0), "v"(a1));
        *(uint32_t*)&yt[l31 * 72 + d] = pw;
      }
    asm volatile("s_waitcnt lgkmcnt(0)" ::: "memory");
    __builtin_amdgcn_sched_barrier(0);
#pragma unroll
    for (int pass = 0; pass < 4; pass++) {
      int rowq = pass * 8 + (lane >> 3);
      int col8 = (lane & 7) * 8;
      u16x8 v = *(const u16x8*)&yt[rowq * 72 + col8];
      *(u16x8*)&yb[((size_t)b * T_SEQ + q0w + rowq) * CDIM + h * DH + col8] = v;
    }
    asm volatile("s_waitcnt lgkmcnt(0)" ::: "memory");
    __builtin_amdgcn_sched_barrier(0);
  };
  EPI(oaccL, lL, q0Lw);
  if (hiAct) EPI(oaccH, lH, q0Hw);
}

// ---------------- launch ----------------
extern "C" void kernel_launch(void* const* d_in, const int* in_sizes, int n_in,
                              void* d_out, int out_size, void* d_ws, size_t ws_size,
                              hipStream_t stream) {
  const float* x  = (const float*)d_in[0];
  const void*  mask = d_in[1];
  const float* Wa = (const float*)d_in[2];
  const float* ba = (const float*)d_in[3];
  const float* Wp = (const float*)d_in[4];
  const float* bp = (const float*)d_in[5];
  float* out = (float*)d_out;

  char* w = (char*)d_ws;
  u16* xb  = (u16*)w; w += (size_t)MROWS * CDIM * 2;   // 16 MB (reused as yb)
  u16* WaT = (u16*)w; w += (size_t)N3 * CDIM * 2;      // 6 MB
  u16* WpT = (u16*)w; w += (size_t)CDIM * CDIM * 2;    // 2 MB
  u16* Qb  = (u16*)w; w += (size_t)MROWS * CDIM * 2;   // 16 MB
  u16* Kb  = (u16*)w; w += (size_t)MROWS * CDIM * 2;   // 16 MB
  u16* Vt  = (u16*)w; w += (size_t)MROWS * CDIM * 2;   // 16 MB  [b,h,d,t]
  int* lengths = (int*)w;                               // 16 B
  u16* yb = xb;  // alias: xb dead after QKV GEMM

  cvt_f32_bf16<<<(MROWS * CDIM / 4 + 255) / 256, 256, 0, stream>>>(x, xb, MROWS * CDIM);
  wt_tiled<<<dim3(N3 / 64, CDIM / 64), 256, 0, stream>>>(Wa, WaT, CDIM, N3);
  wt_tiled<<<dim3(CDIM / 64, CDIM / 64), 256, 0, stream>>>(Wp, WpT, CDIM, CDIM);
  len_kernel<<<BATCH, 256, 0, stream>>>(mask, lengths);

  gemm_bf16<0><<<dim3(N3 / 128, MROWS / 128), 256, 0, stream>>>(
      xb, WaT, ba, Qb, Kb, Vt, nullptr, lengths, MROWS, N3, CDIM);

  attn32p_kernel<<<dim3(8, BATCH * NH), 256, 0, stream>>>(
      Qb, Kb, Vt, yb, lengths);

  gemm_bf16<1><<<dim3(CDIM / 128, MROWS / 128), 256, 0, stream>>>(
      yb, WpT, bp, nullptr, nullptr, nullptr, out, lengths, MROWS, CDIM, CDIM);
}

// Round 16
// 224.050 us; speedup vs baseline: 1.0778x; 1.0302x over previous
//
#include <hip/hip_runtime.h>
#include <stdint.h>

// Problem constants (B=4, T=2048, C=1024, H=16, D=64)
#define T_SEQ 2048
#define CDIM  1024
#define NH    16
#define DH    64
#define BATCH 4
#define MROWS (BATCH * T_SEQ)   // 8192
#define N3    (3 * CDIM)        // 3072
#define NEGBIG -1e30f

typedef unsigned short u16;
typedef __attribute__((ext_vector_type(8))) __bf16 bf16x8;
typedef __attribute__((ext_vector_type(4))) __bf16 bf16x4;
typedef __attribute__((ext_vector_type(8))) unsigned short u16x8;
typedef __attribute__((ext_vector_type(4))) float f32x4;
typedef __attribute__((ext_vector_type(16))) float f32x16;
typedef __attribute__((ext_vector_type(4))) unsigned int u32x4;

__device__ inline u16 f2bf(float f) {
  uint32_t u = __builtin_bit_cast(uint32_t, f);
  u += 0x7FFFu + ((u >> 16) & 1u);   // RNE; inputs finite
  return (u16)(u >> 16);
}

// async global->LDS, 16B per lane; LDS dest = wave-uniform base + lane*16
__device__ inline void gld_lds16(const void* g, void* l) {
  __builtin_amdgcn_global_load_lds(
      (const __attribute__((address_space(1))) void*)g,
      (__attribute__((address_space(3))) void*)l, 16, 0, 0);
}

// ---------------- aux kernels ----------------

__global__ __launch_bounds__(256) void cvt_f32_bf16(
    const float* __restrict__ in, u16* __restrict__ out, int n) {
  int i = (blockIdx.x * 256 + threadIdx.x) * 4;
  if (i >= n) return;
  float4 v = *(const float4*)&in[i];
  ushort4 o; o.x = f2bf(v.x); o.y = f2bf(v.y); o.z = f2bf(v.z); o.w = f2bf(v.w);
  *(ushort4*)&out[i] = o;
}

// W [K][N] fp32 -> WT [N][K] bf16, LDS-tiled (coalesced both sides)
__global__ __launch_bounds__(256) void wt_tiled(
    const float* __restrict__ W, u16* __restrict__ WT, int K, int N) {
  __shared__ float tile[64][65];
  const int k0 = blockIdx.y * 64, n0 = blockIdx.x * 64;
  const int t = threadIdx.x, cr = t >> 6, cc = t & 63;
#pragma unroll
  for (int i = 0; i < 16; i++) {
    int r = i * 4 + cr;
    tile[r][cc] = W[(size_t)(k0 + r) * N + n0 + cc];
  }
  __syncthreads();
#pragma unroll
  for (int i = 0; i < 16; i++) {
    int r = i * 4 + cr;  // output row (n)
    WT[(size_t)(n0 + r) * K + k0 + cc] = f2bf(tile[cc][r]);
  }
}

// lengths[b] = count of non-padded rows; auto-detect int32 vs byte mask.
__global__ __launch_bounds__(256) void len_kernel(
    const void* __restrict__ maskp, int* __restrict__ lengths) {
  __shared__ int flag;
  __shared__ int red[256];
  const int t = threadIdx.x, b = blockIdx.x;
  if (t == 0) flag = 0;
  __syncthreads();
  const uint32_t* mw = (const uint32_t*)maskp;
  int f = 0;
  for (int i = t; i < 2048; i += 256) f |= (mw[i] > 1u) ? 1 : 0;
  if (f) atomicOr(&flag, 1);
  __syncthreads();
  int cnt = 0;
  if (flag) {
    const uint8_t* mb = (const uint8_t*)maskp;
    for (int i = t; i < T_SEQ; i += 256) cnt += (mb[(size_t)b * T_SEQ + i] == 0);
  } else {
    const int* mi = (const int*)maskp;
    for (int i = t; i < T_SEQ; i += 256) cnt += (mi[(size_t)b * T_SEQ + i] == 0);
  }
  red[t] = cnt;
  __syncthreads();
  for (int s = 128; s > 0; s >>= 1) {
    if (t < s) red[t] += red[t + s];
    __syncthreads();
  }
  if (t == 0) lengths[b] = red[0];
}

// ---------------- GEMM: C[M,N] = A[M,K] * Bt[N,K]^T + bias ----------------
// r13-PROVEN 128x128 tile, BK=64, 4 waves, mfma_f32_16x16x32_bf16, XOR-
// swizzled LDS. Padded-row skip. MODE 0: n<2048 -> Q/K via LDS bounce;
// n>=2048 -> V transposed to Vt [b,h,d,t]. MODE 1: fp32 out + zeroing.
template <int MODE>
__global__ __launch_bounds__(256, 2) void gemm_bf16(
    const u16* __restrict__ A, const u16* __restrict__ Bt,
    const float* __restrict__ bias,
    u16* __restrict__ Qb, u16* __restrict__ Kb, u16* __restrict__ Vt,
    float* __restrict__ Out, const int* __restrict__ lengths,
    int Mdim, int Ndim, int Kdim) {
  __shared__ u16 SM[16384];           // As = SM[0:8192], Bs = SM[8192:16384]
  u16* As = SM;
  u16* Bs = SM + 8192;
  const int t = threadIdx.x;
  const int lane = t & 63, wid = t >> 6;
  const int wr = wid >> 1, wc = wid & 1;
  const int r16 = lane & 15, kg = lane >> 4;
  const int m0 = blockIdx.y * 128, n0 = blockIdx.x * 128;
  const int bb = m0 >> 11, tt0 = m0 & 2047;   // batch, within-batch t offset

  if (tt0 >= lengths[bb]) {                   // fully-padded M-tile (uniform)
    if (MODE == 1) {
      const float4 z4 = make_float4(0.f, 0.f, 0.f, 0.f);
#pragma unroll
      for (int i = 0; i < 16; i++) {
        int u = i * 256 + t;
        int r = u >> 5, c4 = u & 31;
        *(float4*)&Out[(size_t)(m0 + r) * CDIM + n0 + c4 * 4] = z4;
      }
    }
    return;
  }

  f32x4 acc[4][4];
#pragma unroll
  for (int i = 0; i < 4; i++)
#pragma unroll
    for (int j = 0; j < 4; j++) acc[i][j] = (f32x4){0.f, 0.f, 0.f, 0.f};

  for (int k0 = 0; k0 < Kdim; k0 += 64) {
#pragma unroll
    for (int i = 0; i < 4; i++) {
      int idx = i * 256 + t;           // 0..1023
      int row = idx >> 3;              // 0..127
      int chunk = idx & 7;
      int colel = (chunk * 8) ^ ((row & 7) << 3);
      gld_lds16(&A[(size_t)(m0 + row) * Kdim + k0 + colel], &As[idx * 8]);
      gld_lds16(&Bt[(size_t)(n0 + row) * Kdim + k0 + colel], &Bs[idx * 8]);
    }
    __syncthreads();

#pragma unroll
    for (int s = 0; s < 2; s++) {
      bf16x8 af[4], bfr[4];
#pragma unroll
      for (int m = 0; m < 4; m++) {
        int row = wr * 64 + m * 16 + r16;
        int colel = (s * 32 + kg * 8) ^ ((row & 7) << 3);
        af[m] = *(const bf16x8*)&As[row * 64 + colel];
      }
#pragma unroll
      for (int n = 0; n < 4; n++) {
        int row = wc * 64 + n * 16 + r16;
        int colel = (s * 32 + kg * 8) ^ ((row & 7) << 3);
        bfr[n] = *(const bf16x8*)&Bs[row * 64 + colel];
      }
#pragma unroll
      for (int m = 0; m < 4; m++)
#pragma unroll
        for (int n = 0; n < 4; n++)
          acc[m][n] = __builtin_amdgcn_mfma_f32_16x16x32_bf16(
              af[m], bfr[n], acc[m][n], 0, 0, 0);
    }
    __syncthreads();
  }

  // epilogue: C/D layout col=lane&15, row=(lane>>4)*4+reg
  if (MODE == 0) {
    const int b = bb;
    if (n0 >= 2048) {
      u16* Tt = SM;  // [128][128], chunk-swizzled
#pragma unroll
      for (int m = 0; m < 4; m++)
#pragma unroll
        for (int n = 0; n < 4; n++) {
          int ln = wc * 64 + n * 16 + r16;
          float bv = bias[n0 + ln];
#pragma unroll
          for (int reg = 0; reg < 4; reg++) {
            int lm = wr * 64 + m * 16 + kg * 4 + reg;
            Tt[ln * 128 + (lm ^ ((ln & 7) << 3))] = f2bf(acc[m][n][reg] + bv);
          }
        }
      __syncthreads();
      const int cbase = n0 - 2048;
#pragma unroll
      for (int i = 0; i < 8; i++) {
        int u = i * 256 + t;
        int ln = u >> 4, ch = u & 15;
        u16x8 v = *(const u16x8*)&Tt[ln * 128 + ((ch * 8) ^ ((ln & 7) << 3))];
        int c = cbase + ln, hh = c >> 6, d = c & 63;
        *(u16x8*)&Vt[(((size_t)b * NH + hh) * DH + d) * T_SEQ + tt0 + ch * 8] = v;
      }
    } else {
      u16* Tt = SM;  // [128 t-rows][128 n-cols], col-swizzled per row
#pragma unroll
      for (int m = 0; m < 4; m++)
#pragma unroll
        for (int n = 0; n < 4; n++) {
          int ln = wc * 64 + n * 16 + r16;
          float bv = bias[n0 + ln];
#pragma unroll
          for (int reg = 0; reg < 4; reg++) {
            int lm = wr * 64 + m * 16 + kg * 4 + reg;
            Tt[lm * 128 + (ln ^ ((lm & 7) << 3))] = f2bf(acc[m][n][reg] + bv);
          }
        }
      __syncthreads();
      const int cb = n0 & 1023;
      u16* dst = (n0 < 1024) ? Qb : Kb;
#pragma unroll
      for (int i = 0; i < 8; i++) {
        int u = i * 256 + t;
        int row = u >> 4, ch = u & 15;
        u16x8 v = *(const u16x8*)&Tt[row * 128 + ((ch * 8) ^ ((row & 7) << 3))];
        int c = cb + ch * 8, hh = c >> 6, d = c & 63;
        *(u16x8*)&dst[((size_t)(b * NH + hh) * T_SEQ + tt0 + row) * DH + d] = v;
      }
    }
    return;
  }

#pragma unroll
  for (int m = 0; m < 4; m++) {
    int gmb = m0 + wr * 64 + m * 16 + kg * 4;
#pragma unroll
    for (int n = 0; n < 4; n++) {
      int gn = n0 + wc * 64 + n * 16 + r16;
      float bv = bias[gn];
#pragma unroll
      for (int reg = 0; reg < 4; reg++) {
        float v = acc[m][n][reg] + bv;
        int row = gmb + reg;           // = b*T + t
        int b = row >> 11, tt = row & 2047;
        if (tt >= lengths[b]) v = 0.f;
        Out[(size_t)row * CDIM + gn] = v;
      }
    }
  }
}

// ---------------- flash attention, length-aware pairs, ring-4 ------------
// r13-proven base (ring-4, 1 barrier/iter, vmcnt(8/4/0), no setprio,
// 121.3 us) + SHFL-ELIMINATION deltas (each ~100cy off the serial chain):
//  (1) cross-half max shfl moved INTO the rescale branch: the defer check
//      __all(tm_half <= mrun+THR) already spans all 64 lanes (both halves),
//      so the wave-uniform skip decision needs only the per-half max.
//      First tile always takes the branch (half-0 holds key kv0+0 <= qrow
//      -> finite tm vs mrun=NEGBIG) -> mrun finite before any exp; masked
//      entries then give exp2(~-1.8e29) = 0 (no NEGBIG-cancel hazard).
//  (2) row-sum shfl removed from the loop: lrun is a PER-HALF partial
//      (fac is half-consistent: mrun updates only under the wave-uniform
//      branch using the true cross-half max); combined once in EPI.
__global__ __launch_bounds__(256) void attn32p_kernel(
    const u16* __restrict__ Qb, const u16* __restrict__ Kb,
    const u16* __restrict__ Vt, u16* __restrict__ yb,
    const int* __restrict__ lengths) {
  __shared__ __attribute__((aligned(16))) char smem[65536];  // 4 x (8K K + 8K V)
  const int t = threadIdx.x, lane = t & 63, wid = t >> 6;
  const int l31 = lane & 31, hi = lane >> 5;
  const int bh = blockIdx.y, b = bh >> 4, h = bh & (NH - 1);
  const int len = lengths[b];
  const int nAct = (len + 127) >> 7;         // active q-tiles (8..16)
  const int npairs = (nAct + 1) >> 1;
  const int iq = blockIdx.x;                 // 0..7
  if (iq >= npairs) return;                  // uniform, before any barrier
  const int q0L = iq * 128;
  const int q0H = (nAct - 1 - iq) * 128;
  const bool hiAct = q0H > q0L;              // middle tile pairs with itself
  const int q0Lw = q0L + wid * 32, q0Hw = q0H + wid * 32;
  const int qrowL = q0Lw + l31, qrowH = q0Hw + l31;
  const u16* Qh = Qb + (size_t)bh * T_SEQ * DH;
  const u16* Kh = Kb + (size_t)bh * T_SEQ * DH;
  const u16* Vth = Vt + (size_t)bh * DH * T_SEQ;
  const float SC = 0.18033688011112042f;     // log2(e) / sqrt(64)
  const float THR = 44.3614195558365f;       // 8 / SC (raw-domain defer thr)

  const int lenceil = (len + 63) & ~63;
  const int kvH = (q0H + 128 < lenceil) ? q0H + 128 : lenceil;
  const int kvL = (q0L + 128 < lenceil) ? q0L + 128 : lenceil;
  const int kv_end = hiAct ? kvH : kvL;
  const int ntiles = kv_end >> 6;            // >= 2 always

  // Q B-fragments for both tiles: B[n=q=l31][k=d=ks*16+hi*8+i]
  bf16x8 qfL[4], qfH[4];
#pragma unroll
  for (int ks = 0; ks < 4; ks++) {
    qfL[ks] = *(const bf16x8*)&Qh[(size_t)qrowL * DH + ks * 16 + hi * 8];
    qfH[ks] = *(const bf16x8*)&Qh[(size_t)qrowH * DH + ks * 16 + hi * 8];
  }

  f32x16 oaccL[2], oaccH[2];
  oaccL[0] = (f32x16)0.f; oaccL[1] = (f32x16)0.f;
  oaccH[0] = (f32x16)0.f; oaccH[1] = (f32x16)0.f;
  float mL = NEGBIG, lL = 0.f, mH = NEGBIG, lH = 0.f;  // l = per-half partial

  // per-lane staging sources (running ptrs; K +8192B/tile, V +128B/tile)
  const int idx0 = t, idx1 = 256 + t;
  const int row0 = idx0 >> 3, ch0 = idx0 & 7;
  const int row1 = idx1 >> 3, ch1 = idx1 & 7;
  const int kc0 = (ch0 * 8) ^ ((row0 & 7) << 3);
  const int kc1 = (ch1 * 8) ^ ((row1 & 7) << 3);
  const char* kp0 = (const char*)Kh + ((size_t)row0 * DH + kc0) * 2;
  const char* kp1 = (const char*)Kh + ((size_t)row1 * DH + kc1) * 2;
  const char* vp0 = (const char*)Vth + ((size_t)row0 * T_SEQ + kc0) * 2;
  const char* vp1 = (const char*)Vth + ((size_t)row1 * T_SEQ + kc1) * 2;

  auto STAGE = [&](int bsel) {               // 4 vm-ops per thread
    char* base = smem + bsel * 16384;
    gld_lds16(kp0, base + idx0 * 16);
    gld_lds16(kp1, base + idx1 * 16);
    gld_lds16(vp0, base + 8192 + idx0 * 16);
    gld_lds16(vp1, base + 8192 + idx1 * 16);
    kp0 += 8192; kp1 += 8192; vp0 += 128; vp1 += 128;
  };

  // one flash step for one q-tile on the staged (Ks,Vts) KV tile
  auto FLASH = [&](const u16* Ks, const u16* Vts, int kv0, int q0w, int qrow,
                   bf16x8* qf, f32x16* oacc, float& mrun, float& lrun) {
    f32x16 sacc[2];
    sacc[0] = (f32x16)0.f; sacc[1] = (f32x16)0.f;
#pragma unroll
    for (int kb = 0; kb < 2; kb++)
#pragma unroll
      for (int ks = 0; ks < 4; ks++) {
        int row = kb * 32 + l31;
        int col = (ks * 16 + hi * 8) ^ ((row & 7) << 3);
        bf16x8 ak = *(const bf16x8*)&Ks[row * 64 + col];
        sacc[kb] = __builtin_amdgcn_mfma_f32_32x32x16_bf16(
            ak, qf[ks], sacc[kb], 0, 0, 0);
      }

    if ((kv0 + 63 > q0w) || (kv0 + 64 > len)) {   // mask (raw domain)
#pragma unroll
      for (int kb = 0; kb < 2; kb++)
#pragma unroll
        for (int r = 0; r < 16; r++) {
          int key = kv0 + kb * 32 + (r & 3) + 8 * (r >> 2) + 4 * hi;
          if (key > qrow || key >= len) sacc[kb][r] = NEGBIG;
        }
    }
    // in-lane tree max (per-half; NO shfl in common path)
    float tm[16];
#pragma unroll
    for (int r = 0; r < 16; r++) tm[r] = fmaxf(sacc[0][r], sacc[1][r]);
#pragma unroll
    for (int r = 0; r < 8; r++) tm[r] = fmaxf(tm[r], tm[r + 8]);
#pragma unroll
    for (int r = 0; r < 4; r++) tm[r] = fmaxf(tm[r], tm[r + 4]);
    tm[0] = fmaxf(fmaxf(tm[0], tm[2]), fmaxf(tm[1], tm[3]));

    // defer-max: __all spans both halves -> wave-uniform skip decision.
    if (!__all(tm[0] <= mrun + THR)) {
      float mt = fmaxf(tm[0], __shfl_xor(tm[0], 32));  // true row max (rare)
      float mnew = fmaxf(mrun, mt);
      float fac = exp2f((mrun - mnew) * SC);
      mrun = mnew;
      lrun *= fac;
#pragma unroll
      for (int r = 0; r < 16; r++) { oacc[0][r] *= fac; oacc[1][r] *= fac; }
    }
    const float msc = mrun * SC;
#pragma unroll
    for (int kb = 0; kb < 2; kb++)
#pragma unroll
      for (int r = 0; r < 16; r++)
        sacc[kb][r] = exp2f(fmaf(sacc[kb][r], SC, -msc));
    // per-half partial row sum (NO shfl; cross-half combine in epilogue)
    float pt[16];
#pragma unroll
    for (int r = 0; r < 16; r++) pt[r] = sacc[0][r] + sacc[1][r];
#pragma unroll
    for (int r = 0; r < 8; r++) pt[r] += pt[r + 8];
#pragma unroll
    for (int r = 0; r < 4; r++) pt[r] += pt[r + 4];
    lrun += (pt[0] + pt[2]) + (pt[1] + pt[3]);

    // O^T += V^T * P^T (slot-permuted, zero cross-lane traffic)
#pragma unroll
    for (int ks = 0; ks < 4; ks++) {
      const int kb = ks >> 1, rb = (ks & 1) * 8;
      uint32_t d0, d1, d2, d3;
      asm("v_cvt_pk_bf16_f32 %0, %1, %2" : "=v"(d0)
          : "v"(sacc[kb][rb + 0]), "v"(sacc[kb][rb + 1]));
      asm("v_cvt_pk_bf16_f32 %0, %1, %2" : "=v"(d1)
          : "v"(sacc[kb][rb + 2]), "v"(sacc[kb][rb + 3]));
      asm("v_cvt_pk_bf16_f32 %0, %1, %2" : "=v"(d2)
          : "v"(sacc[kb][rb + 4]), "v"(sacc[kb][rb + 5]));
      asm("v_cvt_pk_bf16_f32 %0, %1, %2" : "=v"(d3)
          : "v"(sacc[kb][rb + 6]), "v"(sacc[kb][rb + 7]));
      bf16x8 pb = __builtin_bit_cast(bf16x8, (u32x4){d0, d1, d2, d3});
#pragma unroll
      for (int mb = 0; mb < 2; mb++) {
        int row = mb * 32 + l31;
        int sw = (row & 7);
        bf16x4 v1 = *(const bf16x4*)&Vts[row * 64 + ((2 * ks) ^ sw) * 8 + 4 * hi];
        bf16x4 v2 = *(const bf16x4*)&Vts[row * 64 + ((2 * ks + 1) ^ sw) * 8 + 4 * hi];
        bf16x8 av;
#pragma unroll
        for (int j = 0; j < 4; j++) { av[j] = v1[j]; av[4 + j] = v2[j]; }
        oacc[mb] = __builtin_amdgcn_mfma_f32_32x32x16_bf16(
            av, pb, oacc[mb], 0, 0, 0);
      }
    }
  };

  // ring-4 pipeline: S_k issued at iter k-2; one barrier per iter
  STAGE(0); STAGE(1);
  for (int it = 0; it < ntiles; ++it) {
    if (it + 2 < ntiles) STAGE((it + 2) & 3);
    const int r = ntiles - 1 - it;
    if (r >= 2)      asm volatile("s_waitcnt vmcnt(8)" ::: "memory");
    else if (r == 1) asm volatile("s_waitcnt vmcnt(4)" ::: "memory");
    else             asm volatile("s_waitcnt vmcnt(0)" ::: "memory");
    __builtin_amdgcn_s_barrier();
    __builtin_amdgcn_sched_barrier(0);

    const u16* Ks  = (const u16*)(smem + (it & 3) * 16384);
    const u16* Vts = (const u16*)(smem + (it & 3) * 16384 + 8192);
    const int kv0 = it << 6;
    if (hiAct && kv0 <= q0Hw + 31)
      FLASH(Ks, Vts, kv0, q0Hw, qrowH, qfH, oaccH, mH, lH);
    if (kv0 <= q0Lw + 31)
      FLASH(Ks, Vts, kv0, q0Lw, qrowL, qfL, oaccL, mL, lL);
  }
  __syncthreads();  // all compute done before smem reuse as epilogue buffer

  // epilogue: O^T regs -> per-wave LDS [32 q][72 d] -> coalesced global
  u16* yt = (u16*)smem + wid * (32 * 72);
  auto EPI = [&](f32x16* oacc, float lrun, int q0w) {
    float lt = lrun + __shfl_xor(lrun, 32);   // cross-half l combine (once)
    const float inv = (lt > 0.f) ? 1.f / lt : 0.f;
#pragma unroll
    for (int mb = 0; mb < 2; mb++)
#pragma unroll
      for (int r = 0; r < 16; r += 2) {
        int d = mb * 32 + (r & 3) + 8 * (r >> 2) + 4 * hi;
        float a0 = oacc[mb][r] * inv, a1 = oacc[mb][r + 1] * inv;
        uint32_t pw;
        asm("v_cvt_pk_bf16_f32 %0, %1, %2" : "=v"(pw) : "v"(a0), "v"(a1));
        *(uint32_t*)&yt[l31 * 72 + d] = pw;
      }
    asm volatile("s_waitcnt lgkmcnt(0)" ::: "memory");
    __builtin_amdgcn_sched_barrier(0);
#pragma unroll
    for (int pass = 0; pass < 4; pass++) {
      int rowq = pass * 8 + (lane >> 3);
      int col8 = (lane & 7) * 8;
      u16x8 v = *(const u16x8*)&yt[rowq * 72 + col8];
      *(u16x8*)&yb[((size_t)b * T_SEQ + q0w + rowq) * CDIM + h * DH + col8] = v;
    }
    asm volatile("s_waitcnt lgkmcnt(0)" ::: "memory");
    __builtin_amdgcn_sched_barrier(0);
  };
  EPI(oaccL, lL, q0Lw);
  if (hiAct) EPI(oaccH, lH, q0Hw);
}

// ---------------- launch ----------------
extern "C" void kernel_launch(void* const* d_in, const int* in_sizes, int n_in,
                              void* d_out, int out_size, void* d_ws, size_t ws_size,
                              hipStream_t stream) {
  const float* x  = (const float*)d_in[0];
  const void*  mask = d_in[1];
  const float* Wa = (const float*)d_in[2];
  const float* ba = (const float*)d_in[3];
  const float* Wp = (const float*)d_in[4];
  const float* bp = (const float*)d_in[5];
  float* out = (float*)d_out;

  char* w = (char*)d_ws;
  u16* xb  = (u16*)w; w += (size_t)MROWS * CDIM * 2;   // 16 MB (reused as yb)
  u16* WaT = (u16*)w; w += (size_t)N3 * CDIM * 2;      // 6 MB
  u16* WpT = (u16*)w; w += (size_t)CDIM * CDIM * 2;    // 2 MB
  u16* Qb  = (u16*)w; w += (size_t)MROWS * CDIM * 2;   // 16 MB
  u16* Kb  = (u16*)w; w += (size_t)MROWS * CDIM * 2;   // 16 MB
  u16* Vt  = (u16*)w; w += (size_t)MROWS * CDIM * 2;   // 16 MB  [b,h,d,t]
  int* lengths = (int*)w;                               // 16 B
  u16* yb = xb;  // alias: xb dead after QKV GEMM

  cvt_f32_bf16<<<(MROWS * CDIM / 4 + 255) / 256, 256, 0, stream>>>(x, xb, MROWS * CDIM);
  wt_tiled<<<dim3(N3 / 64, CDIM / 64), 256, 0, stream>>>(Wa, WaT, CDIM, N3);
  wt_tiled<<<dim3(CDIM / 64, CDIM / 64), 256, 0, stream>>>(Wp, WpT, CDIM, CDIM);
  len_kernel<<<BATCH, 256, 0, stream>>>(mask, lengths);

  gemm_bf16<0><<<dim3(N3 / 128, MROWS / 128), 256, 0, stream>>>(
      xb, WaT, ba, Qb, Kb, Vt, nullptr, lengths, MROWS, N3, CDIM);

  attn32p_kernel<<<dim3(8, BATCH * NH), 256, 0, stream>>>(
      Qb, Kb, Vt, yb, lengths);

  gemm_bf16<1><<<dim3(CDIM / 128, MROWS / 128), 256, 0, stream>>>(
      yb, WpT, bp, nullptr, nullptr, nullptr, out, lengths, MROWS, CDIM, CDIM);
}

// Round 17
// 218.061 us; speedup vs baseline: 1.1074x; 1.0275x over previous
//
#include <hip/hip_runtime.h>
#include <stdint.h>

// Problem constants (B=4, T=2048, C=1024, H=16, D=64)
#define T_SEQ 2048
#define CDIM  1024
#define NH    16
#define DH    64
#define BATCH 4
#define MROWS (BATCH * T_SEQ)   // 8192
#define N3    (3 * CDIM)        // 3072
#define NEGBIG -1e30f

typedef unsigned short u16;
typedef __attribute__((ext_vector_type(8))) __bf16 bf16x8;
typedef __attribute__((ext_vector_type(4))) __bf16 bf16x4;
typedef __attribute__((ext_vector_type(8))) unsigned short u16x8;
typedef __attribute__((ext_vector_type(4))) float f32x4;
typedef __attribute__((ext_vector_type(16))) float f32x16;
typedef __attribute__((ext_vector_type(4))) unsigned int u32x4;

__device__ inline u16 f2bf(float f) {
  uint32_t u = __builtin_bit_cast(uint32_t, f);
  u += 0x7FFFu + ((u >> 16) & 1u);   // RNE; inputs finite
  return (u16)(u >> 16);
}

// async global->LDS, 16B per lane; LDS dest = wave-uniform base + lane*16
__device__ inline void gld_lds16(const void* g, void* l) {
  __builtin_amdgcn_global_load_lds(
      (const __attribute__((address_space(1))) void*)g,
      (__attribute__((address_space(3))) void*)l, 16, 0, 0);
}

// ---------------- aux kernels ----------------

__global__ __launch_bounds__(256) void cvt_f32_bf16(
    const float* __restrict__ in, u16* __restrict__ out, int n) {
  int i = (blockIdx.x * 256 + threadIdx.x) * 4;
  if (i >= n) return;
  float4 v = *(const float4*)&in[i];
  ushort4 o; o.x = f2bf(v.x); o.y = f2bf(v.y); o.z = f2bf(v.z); o.w = f2bf(v.w);
  *(ushort4*)&out[i] = o;
}

// W [K][N] fp32 -> WT [N][K] bf16, LDS-tiled (coalesced both sides)
__global__ __launch_bounds__(256) void wt_tiled(
    const float* __restrict__ W, u16* __restrict__ WT, int K, int N) {
  __shared__ float tile[64][65];
  const int k0 = blockIdx.y * 64, n0 = blockIdx.x * 64;
  const int t = threadIdx.x, cr = t >> 6, cc = t & 63;
#pragma unroll
  for (int i = 0; i < 16; i++) {
    int r = i * 4 + cr;
    tile[r][cc] = W[(size_t)(k0 + r) * N + n0 + cc];
  }
  __syncthreads();
#pragma unroll
  for (int i = 0; i < 16; i++) {
    int r = i * 4 + cr;  // output row (n)
    WT[(size_t)(n0 + r) * K + k0 + cc] = f2bf(tile[cc][r]);
  }
}

// lengths[b] = count of non-padded rows; auto-detect int32 vs byte mask.
__global__ __launch_bounds__(256) void len_kernel(
    const void* __restrict__ maskp, int* __restrict__ lengths) {
  __shared__ int flag;
  __shared__ int red[256];
  const int t = threadIdx.x, b = blockIdx.x;
  if (t == 0) flag = 0;
  __syncthreads();
  const uint32_t* mw = (const uint32_t*)maskp;
  int f = 0;
  for (int i = t; i < 2048; i += 256) f |= (mw[i] > 1u) ? 1 : 0;
  if (f) atomicOr(&flag, 1);
  __syncthreads();
  int cnt = 0;
  if (flag) {
    const uint8_t* mb = (const uint8_t*)maskp;
    for (int i = t; i < T_SEQ; i += 256) cnt += (mb[(size_t)b * T_SEQ + i] == 0);
  } else {
    const int* mi = (const int*)maskp;
    for (int i = t; i < T_SEQ; i += 256) cnt += (mi[(size_t)b * T_SEQ + i] == 0);
  }
  red[t] = cnt;
  __syncthreads();
  for (int s = 128; s > 0; s >>= 1) {
    if (t < s) red[t] += red[t + s];
    __syncthreads();
  }
  if (t == 0) lengths[b] = red[0];
}

// ---------------- GEMM: C[M,N] = A[M,K] * Bt[N,K]^T + bias ----------------
// r13-PROVEN 128x128 tile, BK=64, 4 waves, mfma_f32_16x16x32_bf16, XOR-
// swizzled LDS. Padded-row skip. MODE 0: n<2048 -> Q/K via LDS bounce;
// n>=2048 -> V transposed to Vt [b,h,d,t]. MODE 1: fp32 out + zeroing.
template <int MODE>
__global__ __launch_bounds__(256, 2) void gemm_bf16(
    const u16* __restrict__ A, const u16* __restrict__ Bt,
    const float* __restrict__ bias,
    u16* __restrict__ Qb, u16* __restrict__ Kb, u16* __restrict__ Vt,
    float* __restrict__ Out, const int* __restrict__ lengths,
    int Mdim, int Ndim, int Kdim) {
  __shared__ u16 SM[16384];           // As = SM[0:8192], Bs = SM[8192:16384]
  u16* As = SM;
  u16* Bs = SM + 8192;
  const int t = threadIdx.x;
  const int lane = t & 63, wid = t >> 6;
  const int wr = wid >> 1, wc = wid & 1;
  const int r16 = lane & 15, kg = lane >> 4;
  const int m0 = blockIdx.y * 128, n0 = blockIdx.x * 128;
  const int bb = m0 >> 11, tt0 = m0 & 2047;   // batch, within-batch t offset

  if (tt0 >= lengths[bb]) {                   // fully-padded M-tile (uniform)
    if (MODE == 1) {
      const float4 z4 = make_float4(0.f, 0.f, 0.f, 0.f);
#pragma unroll
      for (int i = 0; i < 16; i++) {
        int u = i * 256 + t;
        int r = u >> 5, c4 = u & 31;
        *(float4*)&Out[(size_t)(m0 + r) * CDIM + n0 + c4 * 4] = z4;
      }
    }
    return;
  }

  f32x4 acc[4][4];
#pragma unroll
  for (int i = 0; i < 4; i++)
#pragma unroll
    for (int j = 0; j < 4; j++) acc[i][j] = (f32x4){0.f, 0.f, 0.f, 0.f};

  for (int k0 = 0; k0 < Kdim; k0 += 64) {
#pragma unroll
    for (int i = 0; i < 4; i++) {
      int idx = i * 256 + t;           // 0..1023
      int row = idx >> 3;              // 0..127
      int chunk = idx & 7;
      int colel = (chunk * 8) ^ ((row & 7) << 3);
      gld_lds16(&A[(size_t)(m0 + row) * Kdim + k0 + colel], &As[idx * 8]);
      gld_lds16(&Bt[(size_t)(n0 + row) * Kdim + k0 + colel], &Bs[idx * 8]);
    }
    __syncthreads();

#pragma unroll
    for (int s = 0; s < 2; s++) {
      bf16x8 af[4], bfr[4];
#pragma unroll
      for (int m = 0; m < 4; m++) {
        int row = wr * 64 + m * 16 + r16;
        int colel = (s * 32 + kg * 8) ^ ((row & 7) << 3);
        af[m] = *(const bf16x8*)&As[row * 64 + colel];
      }
#pragma unroll
      for (int n = 0; n < 4; n++) {
        int row = wc * 64 + n * 16 + r16;
        int colel = (s * 32 + kg * 8) ^ ((row & 7) << 3);
        bfr[n] = *(const bf16x8*)&Bs[row * 64 + colel];
      }
#pragma unroll
      for (int m = 0; m < 4; m++)
#pragma unroll
        for (int n = 0; n < 4; n++)
          acc[m][n] = __builtin_amdgcn_mfma_f32_16x16x32_bf16(
              af[m], bfr[n], acc[m][n], 0, 0, 0);
    }
    __syncthreads();
  }

  // epilogue: C/D layout col=lane&15, row=(lane>>4)*4+reg
  if (MODE == 0) {
    const int b = bb;
    if (n0 >= 2048) {
      u16* Tt = SM;  // [128][128], chunk-swizzled
#pragma unroll
      for (int m = 0; m < 4; m++)
#pragma unroll
        for (int n = 0; n < 4; n++) {
          int ln = wc * 64 + n * 16 + r16;
          float bv = bias[n0 + ln];
#pragma unroll
          for (int reg = 0; reg < 4; reg++) {
            int lm = wr * 64 + m * 16 + kg * 4 + reg;
            Tt[ln * 128 + (lm ^ ((ln & 7) << 3))] = f2bf(acc[m][n][reg] + bv);
          }
        }
      __syncthreads();
      const int cbase = n0 - 2048;
#pragma unroll
      for (int i = 0; i < 8; i++) {
        int u = i * 256 + t;
        int ln = u >> 4, ch = u & 15;
        u16x8 v = *(const u16x8*)&Tt[ln * 128 + ((ch * 8) ^ ((ln & 7) << 3))];
        int c = cbase + ln, hh = c >> 6, d = c & 63;
        *(u16x8*)&Vt[(((size_t)b * NH + hh) * DH + d) * T_SEQ + tt0 + ch * 8] = v;
      }
    } else {
      u16* Tt = SM;  // [128 t-rows][128 n-cols], col-swizzled per row
#pragma unroll
      for (int m = 0; m < 4; m++)
#pragma unroll
        for (int n = 0; n < 4; n++) {
          int ln = wc * 64 + n * 16 + r16;
          float bv = bias[n0 + ln];
#pragma unroll
          for (int reg = 0; reg < 4; reg++) {
            int lm = wr * 64 + m * 16 + kg * 4 + reg;
            Tt[lm * 128 + (ln ^ ((lm & 7) << 3))] = f2bf(acc[m][n][reg] + bv);
          }
        }
      __syncthreads();
      const int cb = n0 & 1023;
      u16* dst = (n0 < 1024) ? Qb : Kb;
#pragma unroll
      for (int i = 0; i < 8; i++) {
        int u = i * 256 + t;
        int row = u >> 4, ch = u & 15;
        u16x8 v = *(const u16x8*)&Tt[row * 128 + ((ch * 8) ^ ((row & 7) << 3))];
        int c = cb + ch * 8, hh = c >> 6, d = c & 63;
        *(u16x8*)&dst[((size_t)(b * NH + hh) * T_SEQ + tt0 + row) * DH + d] = v;
      }
    }
    return;
  }

#pragma unroll
  for (int m = 0; m < 4; m++) {
    int gmb = m0 + wr * 64 + m * 16 + kg * 4;
#pragma unroll
    for (int n = 0; n < 4; n++) {
      int gn = n0 + wc * 64 + n * 16 + r16;
      float bv = bias[gn];
#pragma unroll
      for (int reg = 0; reg < 4; reg++) {
        float v = acc[m][n][reg] + bv;
        int row = gmb + reg;           // = b*T + t
        int b = row >> 11, tt = row & 2047;
        if (tt >= lengths[b]) v = 0.f;
        Out[(size_t)row * CDIM + gn] = v;
      }
    }
  }
}

// ---------------- flash attention: 2-tile chunks, 1 barrier/chunk --------
// r16-proven body (shfl-free softmax, no setprio, 115.1 us) restructured:
// chunk = 2 KV tiles on the same ring-4 buffers (= ring-2 of chunks).
// Per chunk: {vmcnt(0); s_barrier; sched_barrier; STAGE(next chunk);
//   QK(t0); QK(t1); SM(t0); PV(t0); SM(t1); PV(t1)} — QK(t1) hoisted
// before SM(t0) (sequential semantics preserved; LDS stable) so the MFMA
// pipe stays fed during SM VALU, and PV(t0) MFMA overlaps SM(t1) VALU.
// Barriers/waitcnts halve. STAGE-after-barrier (r15-proven safe form):
// writers of chunk c+1 bufs are post-BARRIER_c; their prior readers
// (chunk c-1) are pre-BARRIER_c. vmcnt(0) cheap: chunk-c loads had a
// full ~2-FLASH compute to land. Odd-ntiles tail: single-tile chunk;
// staging one tile past kv_end is address-safe (<= 2048-64) and unread.
__global__ __launch_bounds__(256) void attn32p_kernel(
    const u16* __restrict__ Qb, const u16* __restrict__ Kb,
    const u16* __restrict__ Vt, u16* __restrict__ yb,
    const int* __restrict__ lengths) {
  __shared__ __attribute__((aligned(16))) char smem[65536];  // 4 x (8K K + 8K V)
  const int t = threadIdx.x, lane = t & 63, wid = t >> 6;
  const int l31 = lane & 31, hi = lane >> 5;
  const int bh = blockIdx.y, b = bh >> 4, h = bh & (NH - 1);
  const int len = lengths[b];
  const int nAct = (len + 127) >> 7;         // active q-tiles (8..16)
  const int npairs = (nAct + 1) >> 1;
  const int iq = blockIdx.x;                 // 0..7
  if (iq >= npairs) return;                  // uniform, before any barrier
  const int q0L = iq * 128;
  const int q0H = (nAct - 1 - iq) * 128;
  const bool hiAct = q0H > q0L;              // middle tile pairs with itself
  const int q0Lw = q0L + wid * 32, q0Hw = q0H + wid * 32;
  const int qrowL = q0Lw + l31, qrowH = q0Hw + l31;
  const u16* Qh = Qb + (size_t)bh * T_SEQ * DH;
  const u16* Kh = Kb + (size_t)bh * T_SEQ * DH;
  const u16* Vth = Vt + (size_t)bh * DH * T_SEQ;
  const float SC = 0.18033688011112042f;     // log2(e) / sqrt(64)
  const float THR = 44.3614195558365f;       // 8 / SC (raw-domain defer thr)

  const int lenceil = (len + 63) & ~63;
  const int kvH = (q0H + 128 < lenceil) ? q0H + 128 : lenceil;
  const int kvL = (q0L + 128 < lenceil) ? q0L + 128 : lenceil;
  const int kv_end = hiAct ? kvH : kvL;
  const int ntiles = kv_end >> 6;            // >= 2 always

  // Q B-fragments for both tiles: B[n=q=l31][k=d=ks*16+hi*8+i]
  bf16x8 qfL[4], qfH[4];
#pragma unroll
  for (int ks = 0; ks < 4; ks++) {
    qfL[ks] = *(const bf16x8*)&Qh[(size_t)qrowL * DH + ks * 16 + hi * 8];
    qfH[ks] = *(const bf16x8*)&Qh[(size_t)qrowH * DH + ks * 16 + hi * 8];
  }

  f32x16 oaccL[2], oaccH[2];
  oaccL[0] = (f32x16)0.f; oaccL[1] = (f32x16)0.f;
  oaccH[0] = (f32x16)0.f; oaccH[1] = (f32x16)0.f;
  float mL = NEGBIG, lL = 0.f, mH = NEGBIG, lH = 0.f;  // l = per-half partial

  // per-lane staging sources (running ptrs; K +8192B/tile, V +128B/tile)
  const int idx0 = t, idx1 = 256 + t;
  const int row0 = idx0 >> 3, ch0 = idx0 & 7;
  const int row1 = idx1 >> 3, ch1 = idx1 & 7;
  const int kc0 = (ch0 * 8) ^ ((row0 & 7) << 3);
  const int kc1 = (ch1 * 8) ^ ((row1 & 7) << 3);
  const char* kp0 = (const char*)Kh + ((size_t)row0 * DH + kc0) * 2;
  const char* kp1 = (const char*)Kh + ((size_t)row1 * DH + kc1) * 2;
  const char* vp0 = (const char*)Vth + ((size_t)row0 * T_SEQ + kc0) * 2;
  const char* vp1 = (const char*)Vth + ((size_t)row1 * T_SEQ + kc1) * 2;

  auto STAGE = [&](int bsel) {               // 4 vm-ops per thread, 1 tile
    char* base = smem + bsel * 16384;
    gld_lds16(kp0, base + idx0 * 16);
    gld_lds16(kp1, base + idx1 * 16);
    gld_lds16(vp0, base + 8192 + idx0 * 16);
    gld_lds16(vp1, base + 8192 + idx1 * 16);
    kp0 += 8192; kp1 += 8192; vp0 += 128; vp1 += 128;
  };

  // QK^T for one tile: sacc = K_tile * Q^T (lane q = l31)
  auto QKT = [&](const u16* Ks, bf16x8* qf, f32x16* sacc) {
    sacc[0] = (f32x16)0.f; sacc[1] = (f32x16)0.f;
#pragma unroll
    for (int kb = 0; kb < 2; kb++)
#pragma unroll
      for (int ks = 0; ks < 4; ks++) {
        int row = kb * 32 + l31;
        int col = (ks * 16 + hi * 8) ^ ((row & 7) << 3);
        bf16x8 ak = *(const bf16x8*)&Ks[row * 64 + col];
        sacc[kb] = __builtin_amdgcn_mfma_f32_32x32x16_bf16(
            ak, qf[ks], sacc[kb], 0, 0, 0);
      }
  };

  // softmax + PV for one tile (r16 body, post-QK part)
  auto SMPV = [&](f32x16* sacc, const u16* Vts, int kv0, int q0w, int qrow,
                  f32x16* oacc, float& mrun, float& lrun) {
    if ((kv0 + 63 > q0w) || (kv0 + 64 > len)) {   // mask (raw domain)
#pragma unroll
      for (int kb = 0; kb < 2; kb++)
#pragma unroll
        for (int r = 0; r < 16; r++) {
          int key = kv0 + kb * 32 + (r & 3) + 8 * (r >> 2) + 4 * hi;
          if (key > qrow || key >= len) sacc[kb][r] = NEGBIG;
        }
    }
    // in-lane tree max (per-half; no shfl in common path)
    float tm[16];
#pragma unroll
    for (int r = 0; r < 16; r++) tm[r] = fmaxf(sacc[0][r], sacc[1][r]);
#pragma unroll
    for (int r = 0; r < 8; r++) tm[r] = fmaxf(tm[r], tm[r + 8]);
#pragma unroll
    for (int r = 0; r < 4; r++) tm[r] = fmaxf(tm[r], tm[r + 4]);
    tm[0] = fmaxf(fmaxf(tm[0], tm[2]), fmaxf(tm[1], tm[3]));

    if (!__all(tm[0] <= mrun + THR)) {       // defer-max; __all spans halves
      float mt = fmaxf(tm[0], __shfl_xor(tm[0], 32));  // true row max (rare)
      float mnew = fmaxf(mrun, mt);
      float fac = exp2f((mrun - mnew) * SC);
      mrun = mnew;
      lrun *= fac;
#pragma unroll
      for (int r = 0; r < 16; r++) { oacc[0][r] *= fac; oacc[1][r] *= fac; }
    }
    const float msc = mrun * SC;
#pragma unroll
    for (int kb = 0; kb < 2; kb++)
#pragma unroll
      for (int r = 0; r < 16; r++)
        sacc[kb][r] = exp2f(fmaf(sacc[kb][r], SC, -msc));
    float pt[16];
#pragma unroll
    for (int r = 0; r < 16; r++) pt[r] = sacc[0][r] + sacc[1][r];
#pragma unroll
    for (int r = 0; r < 8; r++) pt[r] += pt[r + 8];
#pragma unroll
    for (int r = 0; r < 4; r++) pt[r] += pt[r + 4];
    lrun += (pt[0] + pt[2]) + (pt[1] + pt[3]);   // per-half partial

    // O^T += V^T * P^T (slot-permuted, zero cross-lane traffic)
#pragma unroll
    for (int ks = 0; ks < 4; ks++) {
      const int kb = ks >> 1, rb = (ks & 1) * 8;
      uint32_t d0, d1, d2, d3;
      asm("v_cvt_pk_bf16_f32 %0, %1, %2" : "=v"(d0)
          : "v"(sacc[kb][rb + 0]), "v"(sacc[kb][rb + 1]));
      asm("v_cvt_pk_bf16_f32 %0, %1, %2" : "=v"(d1)
          : "v"(sacc[kb][rb + 2]), "v"(sacc[kb][rb + 3]));
      asm("v_cvt_pk_bf16_f32 %0, %1, %2" : "=v"(d2)
          : "v"(sacc[kb][rb + 4]), "v"(sacc[kb][rb + 5]));
      asm("v_cvt_pk_bf16_f32 %0, %1, %2" : "=v"(d3)
          : "v"(sacc[kb][rb + 6]), "v"(sacc[kb][rb + 7]));
      bf16x8 pb = __builtin_bit_cast(bf16x8, (u32x4){d0, d1, d2, d3});
#pragma unroll
      for (int mb = 0; mb < 2; mb++) {
        int row = mb * 32 + l31;
        int sw = (row & 7);
        bf16x4 v1 = *(const bf16x4*)&Vts[row * 64 + ((2 * ks) ^ sw) * 8 + 4 * hi];
        bf16x4 v2 = *(const bf16x4*)&Vts[row * 64 + ((2 * ks + 1) ^ sw) * 8 + 4 * hi];
        bf16x8 av;
#pragma unroll
        for (int j = 0; j < 4; j++) { av[j] = v1[j]; av[4 + j] = v2[j]; }
        oacc[mb] = __builtin_amdgcn_mfma_f32_32x32x16_bf16(
            av, pb, oacc[mb], 0, 0, 0);
      }
    }
  };

  // chunked main loop: chunk = tiles (2c, 2c+1); 1 barrier per chunk
  STAGE(0); STAGE(1);                        // chunk 0
  const int nchunks = (ntiles + 1) >> 1;
  for (int c = 0; c < nchunks; ++c) {
    asm volatile("s_waitcnt vmcnt(0)" ::: "memory");
    __builtin_amdgcn_s_barrier();
    __builtin_amdgcn_sched_barrier(0);
    if (c + 1 < nchunks) {                   // stage next chunk (post-bar)
      STAGE((2 * c + 2) & 3);
      STAGE((2 * c + 3) & 3);
    }

    const int t0 = 2 * c, t1 = 2 * c + 1;
    const int kv0 = t0 << 6, kv1 = t1 << 6;
    const u16* Ks0  = (const u16*)(smem + (t0 & 3) * 16384);
    const u16* Vts0 = (const u16*)(smem + (t0 & 3) * 16384 + 8192);
    const u16* Ks1  = (const u16*)(smem + (t1 & 3) * 16384);
    const u16* Vts1 = (const u16*)(smem + (t1 & 3) * 16384 + 8192);
    const bool t1v = t1 < ntiles;

    if (hiAct && kv0 <= q0Hw + 31) {
      const bool two = t1v && (kv1 <= q0Hw + 31);
      f32x16 s0[2], s1[2];
      QKT(Ks0, qfH, s0);
      if (two) QKT(Ks1, qfH, s1);
      SMPV(s0, Vts0, kv0, q0Hw, qrowH, oaccH, mH, lH);
      if (two) SMPV(s1, Vts1, kv1, q0Hw, qrowH, oaccH, mH, lH);
    }
    if (kv0 <= q0Lw + 31) {
      const bool two = t1v && (kv1 <= q0Lw + 31);
      f32x16 s0[2], s1[2];
      QKT(Ks0, qfL, s0);
      if (two) QKT(Ks1, qfL, s1);
      SMPV(s0, Vts0, kv0, q0Lw, qrowL, oaccL, mL, lL);
      if (two) SMPV(s1, Vts1, kv1, q0Lw, qrowL, oaccL, mL, lL);
    }
  }
  __syncthreads();  // all compute done before smem reuse as epilogue buffer

  // epilogue: O^T regs -> per-wave LDS [32 q][72 d] -> coalesced global
  u16* yt = (u16*)smem + wid * (32 * 72);
  auto EPI = [&](f32x16* oacc, float lrun, int q0w) {
    float lt = lrun + __shfl_xor(lrun, 32);   // cross-half l combine (once)
    const float inv = (lt > 0.f) ? 1.f / lt : 0.f;
#pragma unroll
    for (int mb = 0; mb < 2; mb++)
#pragma unroll
      for (int r = 0; r < 16; r += 2) {
        int d = mb * 32 + (r & 3) + 8 * (r >> 2) + 4 * hi;
        float a0 = oacc[mb][r] * inv, a1 = oacc[mb][r + 1] * inv;
        uint32_t pw;
        asm("v_cvt_pk_bf16_f32 %0, %1, %2" : "=v"(pw) : "v"(a0), "v"(a1));
        *(uint32_t*)&yt[l31 * 72 + d] = pw;
      }
    asm volatile("s_waitcnt lgkmcnt(0)" ::: "memory");
    __builtin_amdgcn_sched_barrier(0);
#pragma unroll
    for (int pass = 0; pass < 4; pass++) {
      int rowq = pass * 8 + (lane >> 3);
      int col8 = (lane & 7) * 8;
      u16x8 v = *(const u16x8*)&yt[rowq * 72 + col8];
      *(u16x8*)&yb[((size_t)b * T_SEQ + q0w + rowq) * CDIM + h * DH + col8] = v;
    }
    asm volatile("s_waitcnt lgkmcnt(0)" ::: "memory");
    __builtin_amdgcn_sched_barrier(0);
  };
  EPI(oaccL, lL, q0Lw);
  if (hiAct) EPI(oaccH, lH, q0Hw);
}

// ---------------- launch ----------------
extern "C" void kernel_launch(void* const* d_in, const int* in_sizes, int n_in,
                              void* d_out, int out_size, void* d_ws, size_t ws_size,
                              hipStream_t stream) {
  const float* x  = (const float*)d_in[0];
  const void*  mask = d_in[1];
  const float* Wa = (const float*)d_in[2];
  const float* ba = (const float*)d_in[3];
  const float* Wp = (const float*)d_in[4];
  const float* bp = (const float*)d_in[5];
  float* out = (float*)d_out;

  char* w = (char*)d_ws;
  u16* xb  = (u16*)w; w += (size_t)MROWS * CDIM * 2;   // 16 MB (reused as yb)
  u16* WaT = (u16*)w; w += (size_t)N3 * CDIM * 2;      // 6 MB
  u16* WpT = (u16*)w; w += (size_t)CDIM * CDIM * 2;    // 2 MB
  u16* Qb  = (u16*)w; w += (size_t)MROWS * CDIM * 2;   // 16 MB
  u16* Kb  = (u16*)w; w += (size_t)MROWS * CDIM * 2;   // 16 MB
  u16* Vt  = (u16*)w; w += (size_t)MROWS * CDIM * 2;   // 16 MB  [b,h,d,t]
  int* lengths = (int*)w;                               // 16 B
  u16* yb = xb;  // alias: xb dead after QKV GEMM

  cvt_f32_bf16<<<(MROWS * CDIM / 4 + 255) / 256, 256, 0, stream>>>(x, xb, MROWS * CDIM);
  wt_tiled<<<dim3(N3 / 64, CDIM / 64), 256, 0, stream>>>(Wa, WaT, CDIM, N3);
  wt_tiled<<<dim3(CDIM / 64, CDIM / 64), 256, 0, stream>>>(Wp, WpT, CDIM, CDIM);
  len_kernel<<<BATCH, 256, 0, stream>>>(mask, lengths);

  gemm_bf16<0><<<dim3(N3 / 128, MROWS / 128), 256, 0, stream>>>(
      xb, WaT, ba, Qb, Kb, Vt, nullptr, lengths, MROWS, N3, CDIM);

  attn32p_kernel<<<dim3(8, BATCH * NH), 256, 0, stream>>>(
      Qb, Kb, Vt, yb, lengths);

  gemm_bf16<1><<<dim3(CDIM / 128, MROWS / 128), 256, 0, stream>>>(
      yb, WpT, bp, nullptr, nullptr, nullptr, out, lengths, MROWS, CDIM, CDIM);
}

// Round 19
// 218.041 us; speedup vs baseline: 1.1075x; 1.0001x over previous
//
#include <hip/hip_runtime.h>
#include <stdint.h>

// Problem constants (B=4, T=2048, C=1024, H=16, D=64)
#define T_SEQ 2048
#define CDIM  1024
#define NH    16
#define DH    64
#define BATCH 4
#define MROWS (BATCH * T_SEQ)   // 8192
#define N3    (3 * CDIM)        // 3072
#define NEGBIG -1e30f

typedef unsigned short u16;
typedef __attribute__((ext_vector_type(8))) __bf16 bf16x8;
typedef __attribute__((ext_vector_type(4))) __bf16 bf16x4;
typedef __attribute__((ext_vector_type(8))) unsigned short u16x8;
typedef __attribute__((ext_vector_type(4))) float f32x4;
typedef __attribute__((ext_vector_type(16))) float f32x16;
typedef __attribute__((ext_vector_type(4))) unsigned int u32x4;

__device__ inline u16 f2bf(float f) {
  uint32_t u = __builtin_bit_cast(uint32_t, f);
  u += 0x7FFFu + ((u >> 16) & 1u);   // RNE; inputs finite
  return (u16)(u >> 16);
}

// async global->LDS, 16B per lane; LDS dest = wave-uniform base + lane*16
__device__ inline void gld_lds16(const void* g, void* l) {
  __builtin_amdgcn_global_load_lds(
      (const __attribute__((address_space(1))) void*)g,
      (__attribute__((address_space(3))) void*)l, 16, 0, 0);
}

// ---------------- aux kernels ----------------

__global__ __launch_bounds__(256) void cvt_f32_bf16(
    const float* __restrict__ in, u16* __restrict__ out, int n) {
  int i = (blockIdx.x * 256 + threadIdx.x) * 4;
  if (i >= n) return;
  float4 v = *(const float4*)&in[i];
  ushort4 o; o.x = f2bf(v.x); o.y = f2bf(v.y); o.z = f2bf(v.z); o.w = f2bf(v.w);
  *(ushort4*)&out[i] = o;
}

// W [K][N] fp32 -> WT [N][K] bf16, LDS-tiled (coalesced both sides)
__global__ __launch_bounds__(256) void wt_tiled(
    const float* __restrict__ W, u16* __restrict__ WT, int K, int N) {
  __shared__ float tile[64][65];
  const int k0 = blockIdx.y * 64, n0 = blockIdx.x * 64;
  const int t = threadIdx.x, cr = t >> 6, cc = t & 63;
#pragma unroll
  for (int i = 0; i < 16; i++) {
    int r = i * 4 + cr;
    tile[r][cc] = W[(size_t)(k0 + r) * N + n0 + cc];
  }
  __syncthreads();
#pragma unroll
  for (int i = 0; i < 16; i++) {
    int r = i * 4 + cr;  // output row (n)
    WT[(size_t)(n0 + r) * K + k0 + cc] = f2bf(tile[cc][r]);
  }
}

// lengths[b] = count of non-padded rows; auto-detect int32 vs byte mask.
__global__ __launch_bounds__(256) void len_kernel(
    const void* __restrict__ maskp, int* __restrict__ lengths) {
  __shared__ int flag;
  __shared__ int red[256];
  const int t = threadIdx.x, b = blockIdx.x;
  if (t == 0) flag = 0;
  __syncthreads();
  const uint32_t* mw = (const uint32_t*)maskp;
  int f = 0;
  for (int i = t; i < 2048; i += 256) f |= (mw[i] > 1u) ? 1 : 0;
  if (f) atomicOr(&flag, 1);
  __syncthreads();
  int cnt = 0;
  if (flag) {
    const uint8_t* mb = (const uint8_t*)maskp;
    for (int i = t; i < T_SEQ; i += 256) cnt += (mb[(size_t)b * T_SEQ + i] == 0);
  } else {
    const int* mi = (const int*)maskp;
    for (int i = t; i < T_SEQ; i += 256) cnt += (mi[(size_t)b * T_SEQ + i] == 0);
  }
  red[t] = cnt;
  __syncthreads();
  for (int s = 128; s > 0; s >>= 1) {
    if (t < s) red[t] += red[t + s];
    __syncthreads();
  }
  if (t == 0) lengths[b] = red[0];
}

// ---------------- GEMM: C[M,N] = A[M,K] * Bt[N,K]^T + bias ----------------
// r13-PROVEN 128x128 tile, BK=64, 4 waves, mfma_f32_16x16x32_bf16, XOR-
// swizzled LDS. Padded-row skip. MODE 0: n<2048 -> Q/K via LDS bounce;
// n>=2048 -> V transposed to Vt [b,h,d,t]. MODE 1: fp32 out + zeroing.
template <int MODE>
__global__ __launch_bounds__(256, 2) void gemm_bf16(
    const u16* __restrict__ A, const u16* __restrict__ Bt,
    const float* __restrict__ bias,
    u16* __restrict__ Qb, u16* __restrict__ Kb, u16* __restrict__ Vt,
    float* __restrict__ Out, const int* __restrict__ lengths,
    int Mdim, int Ndim, int Kdim) {
  __shared__ u16 SM[16384];           // As = SM[0:8192], Bs = SM[8192:16384]
  u16* As = SM;
  u16* Bs = SM + 8192;
  const int t = threadIdx.x;
  const int lane = t & 63, wid = t >> 6;
  const int wr = wid >> 1, wc = wid & 1;
  const int r16 = lane & 15, kg = lane >> 4;
  const int m0 = blockIdx.y * 128, n0 = blockIdx.x * 128;
  const int bb = m0 >> 11, tt0 = m0 & 2047;   // batch, within-batch t offset

  if (tt0 >= lengths[bb]) {                   // fully-padded M-tile (uniform)
    if (MODE == 1) {
      const float4 z4 = make_float4(0.f, 0.f, 0.f, 0.f);
#pragma unroll
      for (int i = 0; i < 16; i++) {
        int u = i * 256 + t;
        int r = u >> 5, c4 = u & 31;
        *(float4*)&Out[(size_t)(m0 + r) * CDIM + n0 + c4 * 4] = z4;
      }
    }
    return;
  }

  f32x4 acc[4][4];
#pragma unroll
  for (int i = 0; i < 4; i++)
#pragma unroll
    for (int j = 0; j < 4; j++) acc[i][j] = (f32x4){0.f, 0.f, 0.f, 0.f};

  for (int k0 = 0; k0 < Kdim; k0 += 64) {
#pragma unroll
    for (int i = 0; i < 4; i++) {
      int idx = i * 256 + t;           // 0..1023
      int row = idx >> 3;              // 0..127
      int chunk = idx & 7;
      int colel = (chunk * 8) ^ ((row & 7) << 3);
      gld_lds16(&A[(size_t)(m0 + row) * Kdim + k0 + colel], &As[idx * 8]);
      gld_lds16(&Bt[(size_t)(n0 + row) * Kdim + k0 + colel], &Bs[idx * 8]);
    }
    __syncthreads();

#pragma unroll
    for (int s = 0; s < 2; s++) {
      bf16x8 af[4], bfr[4];
#pragma unroll
      for (int m = 0; m < 4; m++) {
        int row = wr * 64 + m * 16 + r16;
        int colel = (s * 32 + kg * 8) ^ ((row & 7) << 3);
        af[m] = *(const bf16x8*)&As[row * 64 + colel];
      }
#pragma unroll
      for (int n = 0; n < 4; n++) {
        int row = wc * 64 + n * 16 + r16;
        int colel = (s * 32 + kg * 8) ^ ((row & 7) << 3);
        bfr[n] = *(const bf16x8*)&Bs[row * 64 + colel];
      }
#pragma unroll
      for (int m = 0; m < 4; m++)
#pragma unroll
        for (int n = 0; n < 4; n++)
          acc[m][n] = __builtin_amdgcn_mfma_f32_16x16x32_bf16(
              af[m], bfr[n], acc[m][n], 0, 0, 0);
    }
    __syncthreads();
  }

  // epilogue: C/D layout col=lane&15, row=(lane>>4)*4+reg
  if (MODE == 0) {
    const int b = bb;
    if (n0 >= 2048) {
      u16* Tt = SM;  // [128][128], chunk-swizzled
#pragma unroll
      for (int m = 0; m < 4; m++)
#pragma unroll
        for (int n = 0; n < 4; n++) {
          int ln = wc * 64 + n * 16 + r16;
          float bv = bias[n0 + ln];
#pragma unroll
          for (int reg = 0; reg < 4; reg++) {
            int lm = wr * 64 + m * 16 + kg * 4 + reg;
            Tt[ln * 128 + (lm ^ ((ln & 7) << 3))] = f2bf(acc[m][n][reg] + bv);
          }
        }
      __syncthreads();
      const int cbase = n0 - 2048;
#pragma unroll
      for (int i = 0; i < 8; i++) {
        int u = i * 256 + t;
        int ln = u >> 4, ch = u & 15;
        u16x8 v = *(const u16x8*)&Tt[ln * 128 + ((ch * 8) ^ ((ln & 7) << 3))];
        int c = cbase + ln, hh = c >> 6, d = c & 63;
        *(u16x8*)&Vt[(((size_t)b * NH + hh) * DH + d) * T_SEQ + tt0 + ch * 8] = v;
      }
    } else {
      u16* Tt = SM;  // [128 t-rows][128 n-cols], col-swizzled per row
#pragma unroll
      for (int m = 0; m < 4; m++)
#pragma unroll
        for (int n = 0; n < 4; n++) {
          int ln = wc * 64 + n * 16 + r16;
          float bv = bias[n0 + ln];
#pragma unroll
          for (int reg = 0; reg < 4; reg++) {
            int lm = wr * 64 + m * 16 + kg * 4 + reg;
            Tt[lm * 128 + (ln ^ ((lm & 7) << 3))] = f2bf(acc[m][n][reg] + bv);
          }
        }
      __syncthreads();
      const int cb = n0 & 1023;
      u16* dst = (n0 < 1024) ? Qb : Kb;
#pragma unroll
      for (int i = 0; i < 8; i++) {
        int u = i * 256 + t;
        int row = u >> 4, ch = u & 15;
        u16x8 v = *(const u16x8*)&Tt[row * 128 + ((ch * 8) ^ ((row & 7) << 3))];
        int c = cb + ch * 8, hh = c >> 6, d = c & 63;
        *(u16x8*)&dst[((size_t)(b * NH + hh) * T_SEQ + tt0 + row) * DH + d] = v;
      }
    }
    return;
  }

#pragma unroll
  for (int m = 0; m < 4; m++) {
    int gmb = m0 + wr * 64 + m * 16 + kg * 4;
#pragma unroll
    for (int n = 0; n < 4; n++) {
      int gn = n0 + wc * 64 + n * 16 + r16;
      float bv = bias[gn];
#pragma unroll
      for (int reg = 0; reg < 4; reg++) {
        float v = acc[m][n][reg] + bv;
        int row = gmb + reg;           // = b*T + t
        int b = row >> 11, tt = row & 2047;
        if (tt >= lengths[b]) v = 0.f;
        Out[(size_t)row * CDIM + gn] = v;
      }
    }
  }
}

// ---------------- flash attention: 2-tile chunks, 1 barrier/chunk --------
// r17-PROVEN kernel, byte-identical (109.5 us measured; r18's wave-stagger
// REVERTED after correctness failure). Chunk = 2 KV tiles on ring-4 bufs;
// per chunk: {vmcnt(0); s_barrier; sched_barrier; STAGE(next chunk);
// QK(t0); QK(t1); SM(t0); PV(t0); SM(t1); PV(t1)}. Shfl-free softmax
// (per-half lrun, max-shfl only in rare rescale branch), no setprio.
__global__ __launch_bounds__(256) void attn32p_kernel(
    const u16* __restrict__ Qb, const u16* __restrict__ Kb,
    const u16* __restrict__ Vt, u16* __restrict__ yb,
    const int* __restrict__ lengths) {
  __shared__ __attribute__((aligned(16))) char smem[65536];  // 4 x (8K K + 8K V)
  const int t = threadIdx.x, lane = t & 63, wid = t >> 6;
  const int l31 = lane & 31, hi = lane >> 5;
  const int bh = blockIdx.y, b = bh >> 4, h = bh & (NH - 1);
  const int len = lengths[b];
  const int nAct = (len + 127) >> 7;         // active q-tiles (8..16)
  const int npairs = (nAct + 1) >> 1;
  const int iq = blockIdx.x;                 // 0..7
  if (iq >= npairs) return;                  // uniform, before any barrier
  const int q0L = iq * 128;
  const int q0H = (nAct - 1 - iq) * 128;
  const bool hiAct = q0H > q0L;              // middle tile pairs with itself
  const int q0Lw = q0L + wid * 32, q0Hw = q0H + wid * 32;
  const int qrowL = q0Lw + l31, qrowH = q0Hw + l31;
  const u16* Qh = Qb + (size_t)bh * T_SEQ * DH;
  const u16* Kh = Kb + (size_t)bh * T_SEQ * DH;
  const u16* Vth = Vt + (size_t)bh * DH * T_SEQ;
  const float SC = 0.18033688011112042f;     // log2(e) / sqrt(64)
  const float THR = 44.3614195558365f;       // 8 / SC (raw-domain defer thr)

  const int lenceil = (len + 63) & ~63;
  const int kvH = (q0H + 128 < lenceil) ? q0H + 128 : lenceil;
  const int kvL = (q0L + 128 < lenceil) ? q0L + 128 : lenceil;
  const int kv_end = hiAct ? kvH : kvL;
  const int ntiles = kv_end >> 6;            // >= 2 always

  // Q B-fragments for both tiles: B[n=q=l31][k=d=ks*16+hi*8+i]
  bf16x8 qfL[4], qfH[4];
#pragma unroll
  for (int ks = 0; ks < 4; ks++) {
    qfL[ks] = *(const bf16x8*)&Qh[(size_t)qrowL * DH + ks * 16 + hi * 8];
    qfH[ks] = *(const bf16x8*)&Qh[(size_t)qrowH * DH + ks * 16 + hi * 8];
  }

  f32x16 oaccL[2], oaccH[2];
  oaccL[0] = (f32x16)0.f; oaccL[1] = (f32x16)0.f;
  oaccH[0] = (f32x16)0.f; oaccH[1] = (f32x16)0.f;
  float mL = NEGBIG, lL = 0.f, mH = NEGBIG, lH = 0.f;  // l = per-half partial

  // per-lane staging sources (running ptrs; K +8192B/tile, V +128B/tile)
  const int idx0 = t, idx1 = 256 + t;
  const int row0 = idx0 >> 3, ch0 = idx0 & 7;
  const int row1 = idx1 >> 3, ch1 = idx1 & 7;
  const int kc0 = (ch0 * 8) ^ ((row0 & 7) << 3);
  const int kc1 = (ch1 * 8) ^ ((row1 & 7) << 3);
  const char* kp0 = (const char*)Kh + ((size_t)row0 * DH + kc0) * 2;
  const char* kp1 = (const char*)Kh + ((size_t)row1 * DH + kc1) * 2;
  const char* vp0 = (const char*)Vth + ((size_t)row0 * T_SEQ + kc0) * 2;
  const char* vp1 = (const char*)Vth + ((size_t)row1 * T_SEQ + kc1) * 2;

  auto STAGE = [&](int bsel) {               // 4 vm-ops per thread, 1 tile
    char* base = smem + bsel * 16384;
    gld_lds16(kp0, base + idx0 * 16);
    gld_lds16(kp1, base + idx1 * 16);
    gld_lds16(vp0, base + 8192 + idx0 * 16);
    gld_lds16(vp1, base + 8192 + idx1 * 16);
    kp0 += 8192; kp1 += 8192; vp0 += 128; vp1 += 128;
  };

  // QK^T for one tile: sacc = K_tile * Q^T (lane q = l31)
  auto QKT = [&](const u16* Ks, bf16x8* qf, f32x16* sacc) {
    sacc[0] = (f32x16)0.f; sacc[1] = (f32x16)0.f;
#pragma unroll
    for (int kb = 0; kb < 2; kb++)
#pragma unroll
      for (int ks = 0; ks < 4; ks++) {
        int row = kb * 32 + l31;
        int col = (ks * 16 + hi * 8) ^ ((row & 7) << 3);
        bf16x8 ak = *(const bf16x8*)&Ks[row * 64 + col];
        sacc[kb] = __builtin_amdgcn_mfma_f32_32x32x16_bf16(
            ak, qf[ks], sacc[kb], 0, 0, 0);
      }
  };

  // softmax + PV for one tile
  auto SMPV = [&](f32x16* sacc, const u16* Vts, int kv0, int q0w, int qrow,
                  f32x16* oacc, float& mrun, float& lrun) {
    if ((kv0 + 63 > q0w) || (kv0 + 64 > len)) {   // mask (raw domain)
#pragma unroll
      for (int kb = 0; kb < 2; kb++)
#pragma unroll
        for (int r = 0; r < 16; r++) {
          int key = kv0 + kb * 32 + (r & 3) + 8 * (r >> 2) + 4 * hi;
          if (key > qrow || key >= len) sacc[kb][r] = NEGBIG;
        }
    }
    // in-lane tree max (per-half; no shfl in common path)
    float tm[16];
#pragma unroll
    for (int r = 0; r < 16; r++) tm[r] = fmaxf(sacc[0][r], sacc[1][r]);
#pragma unroll
    for (int r = 0; r < 8; r++) tm[r] = fmaxf(tm[r], tm[r + 8]);
#pragma unroll
    for (int r = 0; r < 4; r++) tm[r] = fmaxf(tm[r], tm[r + 4]);
    tm[0] = fmaxf(fmaxf(tm[0], tm[2]), fmaxf(tm[1], tm[3]));

    if (!__all(tm[0] <= mrun + THR)) {       // defer-max; __all spans halves
      float mt = fmaxf(tm[0], __shfl_xor(tm[0], 32));  // true row max (rare)
      float mnew = fmaxf(mrun, mt);
      float fac = exp2f((mrun - mnew) * SC);
      mrun = mnew;
      lrun *= fac;
#pragma unroll
      for (int r = 0; r < 16; r++) { oacc[0][r] *= fac; oacc[1][r] *= fac; }
    }
    const float msc = mrun * SC;
#pragma unroll
    for (int kb = 0; kb < 2; kb++)
#pragma unroll
      for (int r = 0; r < 16; r++)
        sacc[kb][r] = exp2f(fmaf(sacc[kb][r], SC, -msc));
    float pt[16];
#pragma unroll
    for (int r = 0; r < 16; r++) pt[r] = sacc[0][r] + sacc[1][r];
#pragma unroll
    for (int r = 0; r < 8; r++) pt[r] += pt[r + 8];
#pragma unroll
    for (int r = 0; r < 4; r++) pt[r] += pt[r + 4];
    lrun += (pt[0] + pt[2]) + (pt[1] + pt[3]);   // per-half partial

    // O^T += V^T * P^T (slot-permuted, zero cross-lane traffic)
#pragma unroll
    for (int ks = 0; ks < 4; ks++) {
      const int kb = ks >> 1, rb = (ks & 1) * 8;
      uint32_t d0, d1, d2, d3;
      asm("v_cvt_pk_bf16_f32 %0, %1, %2" : "=v"(d0)
          : "v"(sacc[kb][rb + 0]), "v"(sacc[kb][rb + 1]));
      asm("v_cvt_pk_bf16_f32 %0, %1, %2" : "=v"(d1)
          : "v"(sacc[kb][rb + 2]), "v"(sacc[kb][rb + 3]));
      asm("v_cvt_pk_bf16_f32 %0, %1, %2" : "=v"(d2)
          : "v"(sacc[kb][rb + 4]), "v"(sacc[kb][rb + 5]));
      asm("v_cvt_pk_bf16_f32 %0, %1, %2" : "=v"(d3)
          : "v"(sacc[kb][rb + 6]), "v"(sacc[kb][rb + 7]));
      bf16x8 pb = __builtin_bit_cast(bf16x8, (u32x4){d0, d1, d2, d3});
#pragma unroll
      for (int mb = 0; mb < 2; mb++) {
        int row = mb * 32 + l31;
        int sw = (row & 7);
        bf16x4 v1 = *(const bf16x4*)&Vts[row * 64 + ((2 * ks) ^ sw) * 8 + 4 * hi];
        bf16x4 v2 = *(const bf16x4*)&Vts[row * 64 + ((2 * ks + 1) ^ sw) * 8 + 4 * hi];
        bf16x8 av;
#pragma unroll
        for (int j = 0; j < 4; j++) { av[j] = v1[j]; av[4 + j] = v2[j]; }
        oacc[mb] = __builtin_amdgcn_mfma_f32_32x32x16_bf16(
            av, pb, oacc[mb], 0, 0, 0);
      }
    }
  };

  // chunked main loop: chunk = tiles (2c, 2c+1); 1 barrier per chunk
  STAGE(0); STAGE(1);                        // chunk 0
  const int nchunks = (ntiles + 1) >> 1;
  for (int c = 0; c < nchunks; ++c) {
    asm volatile("s_waitcnt vmcnt(0)" ::: "memory");
    __builtin_amdgcn_s_barrier();
    __builtin_amdgcn_sched_barrier(0);
    if (c + 1 < nchunks) {                   // stage next chunk (post-bar)
      STAGE((2 * c + 2) & 3);
      STAGE((2 * c + 3) & 3);
    }

    const int t0 = 2 * c, t1 = 2 * c + 1;
    const int kv0 = t0 << 6, kv1 = t1 << 6;
    const u16* Ks0  = (const u16*)(smem + (t0 & 3) * 16384);
    const u16* Vts0 = (const u16*)(smem + (t0 & 3) * 16384 + 8192);
    const u16* Ks1  = (const u16*)(smem + (t1 & 3) * 16384);
    const u16* Vts1 = (const u16*)(smem + (t1 & 3) * 16384 + 8192);
    const bool t1v = t1 < ntiles;

    if (hiAct && kv0 <= q0Hw + 31) {
      const bool two = t1v && (kv1 <= q0Hw + 31);
      f32x16 s0[2], s1[2];
      QKT(Ks0, qfH, s0);
      if (two) QKT(Ks1, qfH, s1);
      SMPV(s0, Vts0, kv0, q0Hw, qrowH, oaccH, mH, lH);
      if (two) SMPV(s1, Vts1, kv1, q0Hw, qrowH, oaccH, mH, lH);
    }
    if (kv0 <= q0Lw + 31) {
      const bool two = t1v && (kv1 <= q0Lw + 31);
      f32x16 s0[2], s1[2];
      QKT(Ks0, qfL, s0);
      if (two) QKT(Ks1, qfL, s1);
      SMPV(s0, Vts0, kv0, q0Lw, qrowL, oaccL, mL, lL);
      if (two) SMPV(s1, Vts1, kv1, q0Lw, qrowL, oaccL, mL, lL);
    }
  }
  __syncthreads();  // all compute done before smem reuse as epilogue buffer

  // epilogue: O^T regs -> per-wave LDS [32 q][72 d] -> coalesced global
  u16* yt = (u16*)smem + wid * (32 * 72);
  auto EPI = [&](f32x16* oacc, float lrun, int q0w) {
    float lt = lrun + __shfl_xor(lrun, 32);   // cross-half l combine (once)
    const float inv = (lt > 0.f) ? 1.f / lt : 0.f;
#pragma unroll
    for (int mb = 0; mb < 2; mb++)
#pragma unroll
      for (int r = 0; r < 16; r += 2) {
        int d = mb * 32 + (r & 3) + 8 * (r >> 2) + 4 * hi;
        float a0 = oacc[mb][r] * inv, a1 = oacc[mb][r + 1] * inv;
        uint32_t pw;
        asm("v_cvt_pk_bf16_f32 %0, %1, %2" : "=v"(pw) : "v"(a0), "v"(a1));
        *(uint32_t*)&yt[l31 * 72 + d] = pw;
      }
    asm volatile("s_waitcnt lgkmcnt(0)" ::: "memory");
    __builtin_amdgcn_sched_barrier(0);
#pragma unroll
    for (int pass = 0; pass < 4; pass++) {
      int rowq = pass * 8 + (lane >> 3);
      int col8 = (lane & 7) * 8;
      u16x8 v = *(const u16x8*)&yt[rowq * 72 + col8];
      *(u16x8*)&yb[((size_t)b * T_SEQ + q0w + rowq) * CDIM + h * DH + col8] = v;
    }
    asm volatile("s_waitcnt lgkmcnt(0)" ::: "memory");
    __builtin_amdgcn_sched_barrier(0);
  };
  EPI(oaccL, lL, q0Lw);
  if (hiAct) EPI(oaccH, lH, q0Hw);
}

// ---------------- launch ----------------
extern "C" void kernel_launch(void* const* d_in, const int* in_sizes, int n_in,
                              void* d_out, int out_size, void* d_ws, size_t ws_size,
                              hipStream_t stream) {
  const float* x  = (const float*)d_in[0];
  const void*  mask = d_in[1];
  const float* Wa = (const float*)d_in[2];
  const float* ba = (const float*)d_in[3];
  const float* Wp = (const float*)d_in[4];
  const float* bp = (const float*)d_in[5];
  float* out = (float*)d_out;

  char* w = (char*)d_ws;
  u16* xb  = (u16*)w; w += (size_t)MROWS * CDIM * 2;   // 16 MB (reused as yb)
  u16* WaT = (u16*)w; w += (size_t)N3 * CDIM * 2;      // 6 MB
  u16* WpT = (u16*)w; w += (size_t)CDIM * CDIM * 2;    // 2 MB
  u16* Qb  = (u16*)w; w += (size_t)MROWS * CDIM * 2;   // 16 MB
  u16* Kb  = (u16*)w; w += (size_t)MROWS * CDIM * 2;   // 16 MB
  u16* Vt  = (u16*)w; w += (size_t)MROWS * CDIM * 2;   // 16 MB  [b,h,d,t]
  int* lengths = (int*)w;                               // 16 B
  u16* yb = xb;  // alias: xb dead after QKV GEMM

  cvt_f32_bf16<<<(MROWS * CDIM / 4 + 255) / 256, 256, 0, stream>>>(x, xb, MROWS * CDIM);
  wt_tiled<<<dim3(N3 / 64, CDIM / 64), 256, 0, stream>>>(Wa, WaT, CDIM, N3);
  wt_tiled<<<dim3(CDIM / 64, CDIM / 64), 256, 0, stream>>>(Wp, WpT, CDIM, CDIM);
  len_kernel<<<BATCH, 256, 0, stream>>>(mask, lengths);

  gemm_bf16<0><<<dim3(N3 / 128, MROWS / 128), 256, 0, stream>>>(
      xb, WaT, ba, Qb, Kb, Vt, nullptr, lengths, MROWS, N3, CDIM);

  attn32p_kernel<<<dim3(8, BATCH * NH), 256, 0, stream>>>(
      Qb, Kb, Vt, yb, lengths);

  gemm_bf16<1><<<dim3(CDIM / 128, MROWS / 128), 256, 0, stream>>>(
      yb, WpT, bp, nullptr, nullptr, nullptr, out, lengths, MROWS, CDIM, CDIM);
}